// Round 12
// baseline (467.372 us; speedup 1.0000x reference)
//
#include <hip/hip_runtime.h>
#include <hip/hip_bf16.h>
#include <cstdint>
#include <cstddef>

using bf16 = __hip_bfloat16;
typedef __attribute__((ext_vector_type(4))) float f32x4;
typedef __attribute__((ext_vector_type(8))) short bf16x8;

#define B_ 128
#define L_ 196
#define T_ 25
#define V_ 10000

__device__ __forceinline__ float b2f(short s) {
  unsigned u = ((unsigned)(unsigned short)s) << 16;
  return __uint_as_float(u);
}
__device__ __forceinline__ bf16 f2b(float f) { return __float2bfloat16(f); }
__device__ __forceinline__ short f2bs(float f) {
  return __builtin_bit_cast(short, __float2bfloat16(f));
}
__device__ __forceinline__ float sigf(float x) { return 1.f / (1.f + __expf(-x)); }
__device__ __forceinline__ float tanh_fast(float x) { return 1.f - 2.f / (1.f + __expf(2.f * x)); }

// sc1 write-through stores (push to L3); relaxed agent-scope loads for spin.
__device__ __forceinline__ void cst_u32(unsigned* p, unsigned v) {
  __hip_atomic_store(p, v, __ATOMIC_RELAXED, __HIP_MEMORY_SCOPE_AGENT);
}
__device__ __forceinline__ unsigned cld_u32(const unsigned* p) {
  return __hip_atomic_load((unsigned*)p, __ATOMIC_RELAXED, __HIP_MEMORY_SCOPE_AGENT);
}

// Fragment-packed layout: 16x32 tiles, tile-row-major; element (r,c) at
// (((r>>4)*KT + (c>>5))*64 + ((c&31)>>3)*16 + (r&15))*8 + (c&7).
__device__ __forceinline__ size_t pidx(int row, int col, int K) {
  int KT = K >> 5;
  return (((size_t)(row >> 4) * KT + (col >> 5)) * 64 +
          (size_t)(((col & 31) >> 3) * 16 + (row & 15))) * 8 + (col & 7);
}

__device__ __forceinline__ float wred_sum(float x) {
#pragma unroll
  for (int off = 32; off >= 1; off >>= 1) x += __shfl_xor(x, off, 64);
  return x;
}
__device__ __forceinline__ float wred_max(float x) {
#pragma unroll
  for (int off = 32; off >= 1; off >>= 1) x = fmaxf(x, __shfl_xor(x, off, 64));
  return x;
}

// ---- per-mi-group (32-block) barrier: 4 shards x 8, relaxed atomics only ----
__device__ __forceinline__ void gbar32(unsigned* bs, int mi, int di) {
  asm volatile("s_waitcnt vmcnt(0)" ::: "memory");
  __syncthreads();
  if (threadIdx.x == 0) {
    unsigned* base = bs + mi * 256;     // 1KB per group
    unsigned* gen  = base + 160;
    unsigned g = cld_u32(gen);
    unsigned a = __hip_atomic_fetch_add(base + (di & 3) * 32, 1u, __ATOMIC_RELAXED,
                                        __HIP_MEMORY_SCOPE_AGENT);
    bool rel = false;
    if ((a & 7u) == 7u) {
      unsigned b = __hip_atomic_fetch_add(base + 128, 1u, __ATOMIC_RELAXED,
                                          __HIP_MEMORY_SCOPE_AGENT);
      if ((b & 3u) == 3u) { cst_u32(gen, g + 1u); rel = true; }
    }
    if (!rel) {
      while (cld_u32(gen) == g) __builtin_amdgcn_s_sleep(1);
    }
  }
  __syncthreads();
}

// ---- persistent scan: weight-stationary, 256 blocks = 8 mi x 32 di ----
__global__ __launch_bounds__(256) void scan_ws(
    bf16* __restrict__ hbuf,        // (T_+1) x (128x512 packed) h state
    const bf16* __restrict__ WT_gh, // 2560x512 packed (h-half weights)
    const bf16* __restrict__ xg,    // T_ x 128 x 2560 bf16 row-major: x@W + bias
    float* __restrict__ cbuf,       // 128x512 f32 cell state
    bf16* __restrict__ Aag,         // T_ x 128x1024 packed [h|s]  (post-scan)
    bf16* __restrict__ projA,       // T_ x 128x1024 packed [h|ctx] (post-scan)
    unsigned* __restrict__ bar)
{
  const int tid = threadIdx.x;
  const int wv = tid >> 6, lane = tid & 63;
  const int mi = blockIdx.x >> 5;       // 0..7 (rows mi*16..+15)
  const int di = blockIdx.x & 31;       // 0..31 (cols di*16..+15)
  __shared__ f32x4 pacc[4][5][64];      // 20 KB split-K partials

  // ---- weight-stationary B fragments: bw[g][kk], kt = wv*4+kk ----
  bf16x8 bw[5][4];
#pragma unroll
  for (int g = 0; g < 5; g++)
#pragma unroll
    for (int kk = 0; kk < 4; kk++)
      bw[g][kk] = *(const bf16x8*)(const void*)(
          WT_gh + (size_t)(g * 32 + di) * 8192 + (size_t)(wv * 4 + kk) * 512 + lane * 8);

  const int el_r16 = lane & 15, el_r = lane >> 4;
  const int m_pw = mi * 16 + wv * 4 + el_r;
  const int d_pw = di * 16 + el_r16;
  const size_t qlo = pidx(m_pw, d_pw, 512);
  const size_t plo = pidx(m_pw, d_pw, 1024);
  const size_t phi = pidx(m_pw, 512 + d_pw, 1024);
  float* cp = cbuf + m_pw * 512 + d_pw;

  for (int tt = 0; tt < T_; ++tt) {
    const short* xr = (const short*)(const void*)(
        xg + (size_t)tt * (128 * 2560) + (size_t)m_pw * 2560 + d_pw);
    float xv0 = b2f(xr[0]);
    float xv1 = b2f(xr[512]);
    float xv2 = b2f(xr[1024]);
    float xv3 = b2f(xr[1536]);
    float xv4 = b2f(xr[2048]);
    const bf16* ap = hbuf + (size_t)tt * 65536 + (size_t)mi * 8192 + lane * 8;
    bf16x8 a0 = *(const bf16x8*)(const void*)(ap + (size_t)(wv * 4 + 0) * 512);
    bf16x8 a1 = *(const bf16x8*)(const void*)(ap + (size_t)(wv * 4 + 1) * 512);
    bf16x8 a2 = *(const bf16x8*)(const void*)(ap + (size_t)(wv * 4 + 2) * 512);
    bf16x8 a3 = *(const bf16x8*)(const void*)(ap + (size_t)(wv * 4 + 3) * 512);
    f32x4 acc[5];
#pragma unroll
    for (int g = 0; g < 5; g++) acc[g] = f32x4{0.f, 0.f, 0.f, 0.f};
#pragma unroll
    for (int g = 0; g < 5; g++) {
      acc[g] = __builtin_amdgcn_mfma_f32_16x16x32_bf16(a0, bw[g][0], acc[g], 0, 0, 0);
      acc[g] = __builtin_amdgcn_mfma_f32_16x16x32_bf16(a1, bw[g][1], acc[g], 0, 0, 0);
      acc[g] = __builtin_amdgcn_mfma_f32_16x16x32_bf16(a2, bw[g][2], acc[g], 0, 0, 0);
      acc[g] = __builtin_amdgcn_mfma_f32_16x16x32_bf16(a3, bw[g][3], acc[g], 0, 0, 0);
    }
#pragma unroll
    for (int g = 0; g < 5; g++) pacc[wv][g][lane] = acc[g];
    __syncthreads();
    float G0 = 0.f, G1 = 0.f, G2 = 0.f, G3 = 0.f, G4 = 0.f;
#pragma unroll
    for (int q = 0; q < 4; q++) {
      int sl = wv * 16 + el_r16;
      G0 += pacc[q][0][sl][el_r];
      G1 += pacc[q][1][sl][el_r];
      G2 += pacc[q][2][sl][el_r];
      G3 += pacc[q][3][sl][el_r];
      G4 += pacc[q][4][sl][el_r];
    }
    float cn = sigf(G1 + xv1) * (*cp) + sigf(G0 + xv0) * tanh_fast(G2 + xv2);
    float tcn = tanh_fast(cn);
    float hn = sigf(G3 + xv3) * tcn;
    float ss = sigf(G4 + xv4) * tcn;
    float hn1 = __shfl_down(hn, 1);
    float ss1 = __shfl_down(ss, 1);
    unsigned hp = 0, sp = 0;
    bool wr = !(el_r16 & 1);
    if (wr) {
      hp = (unsigned)(unsigned short)f2bs(hn) |
           ((unsigned)(unsigned short)f2bs(hn1) << 16);
      sp = (unsigned)(unsigned short)f2bs(ss) |
           ((unsigned)(unsigned short)f2bs(ss1) << 16);
      cst_u32((unsigned*)(void*)(hbuf + (size_t)(tt + 1) * 65536 + qlo), hp);
    }
    if (tt < T_ - 1) gbar32(bar, mi, di);
    *cp = cn;
    if (wr) {
      bf16* pA = projA + (size_t)tt * 131072;
      bf16* AagT = Aag + (size_t)tt * 131072;
      *(unsigned*)(void*)(pA + plo) = hp;
      *(unsigned*)(void*)(AagT + plo) = hp;
      *(unsigned*)(void*)(AagT + phi) = sp;
    }
  }
}

// ---- batched e-scores + softmax; grid (128, 25) ----
// attv and agsw now store TANH of the pre-activations, so per element
//   tanh(a+b) = (Ta+Tb)/(1+Ta*Tb)   -> 1 rcp, no exp2.
__global__ __launch_bounds__(256) void e_batch(
    const bf16* __restrict__ attv, const bf16* __restrict__ agsw_all,
    const float* __restrict__ w_a, const int* __restrict__ clen,
    float* __restrict__ alphas, float* __restrict__ betas,
    float* __restrict__ alphas_raw, float* __restrict__ betas_raw)
{
  __shared__ float sh[200];
  __shared__ float red[8];
  int b = blockIdx.x, t = blockIdx.y;
  int tid = threadIdx.x, wv = tid >> 6, lane = tid & 63;
  const bf16* ag = agsw_all + ((size_t)t * 128 + b) * 1024;
  int a0 = lane * 8;
  float ag8[8], wa8[8], sw8[8];
  bf16x8 agv = *(const bf16x8*)(const void*)(ag + a0);
  bf16x8 swv = *(const bf16x8*)(const void*)(ag + 512 + a0);
#pragma unroll
  for (int j = 0; j < 8; j++) {
    ag8[j] = b2f(agv[j]);
    wa8[j] = w_a[a0 + j];
    sw8[j] = b2f(swv[j]);
  }
  for (int base = wv; base < 197; base += 16) {
    bf16x8 av[4];
#pragma unroll
    for (int q = 0; q < 4; q++) {
      int l = base + 4 * q;
      if (l < 196)
        av[q] = *(const bf16x8*)(const void*)(attv + ((size_t)(b * 196 + l)) * 512 + a0);
    }
#pragma unroll
    for (int q = 0; q < 4; q++) {
      int l = base + 4 * q;
      if (l > 196) continue;    // wave-uniform
      float part = 0.f;
      if (l < 196) {
#pragma unroll
        for (int j = 0; j < 8; j++) {
          float Ta = b2f(av[q][j]);
          float den = fmaf(Ta, ag8[j], 1.f);
          float num = Ta + ag8[j];
          part = fmaf(num * __builtin_amdgcn_rcpf(den), wa8[j], part);
        }
      } else {
#pragma unroll
        for (int j = 0; j < 8; j++) {
          float Ta = sw8[j];
          float den = fmaf(Ta, ag8[j], 1.f);
          float num = Ta + ag8[j];
          part = fmaf(num * __builtin_amdgcn_rcpf(den), wa8[j], part);
        }
      }
      part = wred_sum(part);
      if (lane == 0) sh[l] = part;
    }
  }
  __syncthreads();
  float v = (tid < 197) ? sh[tid] : -1e30f;
  float mx = wred_max(v);
  if (lane == 0) red[wv] = mx;
  __syncthreads();
  mx = fmaxf(fmaxf(red[0], red[1]), fmaxf(red[2], red[3]));
  float p = (tid < 197) ? __expf(v - mx) : 0.f;
  float sm = wred_sum(p);
  if (lane == 0) red[4 + wv] = sm;
  __syncthreads();
  float inv = 1.f / (red[4] + red[5] + red[6] + red[7]);
  float a = p * inv;
  int dec = clen[b] - 1; if (dec < 1) dec = 1;
  float act = (t < dec) ? 1.f : 0.f;
  if (tid < 196) {
    alphas[(size_t)b * (T_ * L_) + (size_t)t * L_ + tid] = a * act;
    alphas_raw[(size_t)b * (T_ * L_) + (size_t)t * L_ + tid] = a;
  }
  if (tid == 196) {
    betas[b * T_ + t] = a * act;
    betas_raw[b * T_ + t] = a;
  }
}

// ---- tail: ctx(b,t,:) = alpha_raw(b,t,:) @ enc(b) + beta*s ; write projA ctx ----
__global__ __launch_bounds__(256) void ctx_tail(
    const float* __restrict__ alphas_raw, const float* __restrict__ betas_raw,
    const bf16* __restrict__ enc_r, const bf16* __restrict__ Aag,
    bf16* __restrict__ projA)
{
  int b = blockIdx.x, cs = blockIdx.y, tid = threadIdx.x;
  __shared__ float al[T_ * 200];
  for (int i = tid; i < T_ * 196; i += 256) {
    al[(i / 196) * 200 + (i % 196)] = alphas_raw[(size_t)b * (T_ * 196) + i];
  }
  __syncthreads();
  int ch = cs * 256 + tid;
  float acc[T_];
#pragma unroll
  for (int t = 0; t < T_; t++) acc[t] = 0.f;
  const short* ep = (const short*)(const void*)(enc_r) + (size_t)b * 196 * 512 + ch;
#pragma unroll 4
  for (int l = 0; l < 196; l++) {
    float e = b2f(ep[(size_t)l * 512]);
#pragma unroll
    for (int t = 0; t < T_; t++) acc[t] += al[t * 200 + l] * e;
  }
#pragma unroll
  for (int t = 0; t < T_; t++) {
    float beta = betas_raw[b * T_ + t];
    float sv = b2f(((const short*)(const void*)Aag)[(size_t)t * 131072 + pidx(b, 512 + ch, 1024)]);
    projA[(size_t)t * 131072 + pidx(b, 512 + ch, 1024)] = f2b(acc[t] + beta * sv);
  }
}

enum { EPI_F32 = 0, EPI_BF16 = 1, EPI_INIT = 2, EPI_PROJ = 3, EPI_OUT = 4, EPI_TANH = 5 };

// C = A (MxK packed) @ BT^T (BT: NxK packed), + bias.
template<int MFRAG, int NFRAG, int EPI>
__global__ __launch_bounds__(256) void gemm_pk(
    const bf16* __restrict__ A, const bf16* __restrict__ BT,
    const float* __restrict__ bias, void* __restrict__ Cp,
    const bf16* __restrict__ auxA, float* __restrict__ auxB,
    int M, int N, int K, int ldc, float oscale)
{
  const int lane = threadIdx.x & 63;
  const int wv = threadIdx.x >> 6;
  const int r16 = lane & 15;
  const int kg = lane >> 4;
  const int m0 = blockIdx.x * (MFRAG * 16);
  const int n0 = blockIdx.y * (NFRAG * 64) + wv * (NFRAG * 16);
  const int KT = K >> 5;

  f32x4 acc[MFRAG][NFRAG];
#pragma unroll
  for (int i = 0; i < MFRAG; i++)
#pragma unroll
    for (int j = 0; j < NFRAG; j++) acc[i][j] = f32x4{0.f, 0.f, 0.f, 0.f};

  const bf16* ap = A + (size_t)(m0 >> 4) * KT * 512 + lane * 8;
  const bf16* bp = BT + (size_t)(n0 >> 4) * KT * 512 + lane * 8;

#pragma unroll 4
  for (int kt = 0; kt < KT; kt++) {
    bf16x8 af[MFRAG], bfr[NFRAG];
#pragma unroll
    for (int i = 0; i < MFRAG; i++)
      af[i] = *(const bf16x8*)(const void*)(ap + ((size_t)i * KT + kt) * 512);
#pragma unroll
    for (int j = 0; j < NFRAG; j++)
      bfr[j] = *(const bf16x8*)(const void*)(bp + ((size_t)j * KT + kt) * 512);
#pragma unroll
    for (int i = 0; i < MFRAG; i++)
#pragma unroll
      for (int j = 0; j < NFRAG; j++)
        acc[i][j] = __builtin_amdgcn_mfma_f32_16x16x32_bf16(af[i], bfr[j], acc[i][j], 0, 0, 0);
  }

#pragma unroll
  for (int i = 0; i < MFRAG; i++)
#pragma unroll
    for (int j = 0; j < NFRAG; j++)
#pragma unroll
      for (int r = 0; r < 4; r++) {
        int m = m0 + i * 16 + kg * 4 + r;
        int n = n0 + j * 16 + r16;
        if (n >= N) continue;
        float v = acc[i][j][r] + bias[n];
        if constexpr (EPI == EPI_F32) {
          ((float*)Cp)[(size_t)m * ldc + n] = v * oscale;
        } else if constexpr (EPI == EPI_BF16) {
          ((bf16*)Cp)[(size_t)m * ldc + n] = f2b(v * oscale);
        } else if constexpr (EPI == EPI_TANH) {
          ((bf16*)Cp)[(size_t)m * ldc + n] = f2b(tanh_fast(v));
        } else if constexpr (EPI == EPI_INIT) {
          float tv = tanhf(v);
          if (n < 512) ((bf16*)Cp)[pidx(m, n, 512)] = f2b(tv);   // h0 -> hbuf[0]
          else auxB[(size_t)m * 512 + (n - 512)] = tv;           // c0 (f32)
        } else if constexpr (EPI == EPI_PROJ) {
          v += b2f(((const short*)auxA)[pidx(m, n, 512)]);       // + x (xbuf)
          ((bf16*)Cp)[pidx(m, n, 512)] = f2b(v);
        } else {  // EPI_OUT: preds[b, t, n], row = t*128+b
          int t = m >> 7, b = m & 127;
          ((float*)Cp)[(size_t)b * (T_ * V_) + (size_t)t * V_ + n] = v;
        }
      }
}

// ---- fused multi-job packed-transpose ----
#define NJOBS 10
struct TJobs {
  const float* top[NJOBS];
  const float* bot[NJOBS];
  bf16* dst[NJOBS];
  int ncols[NJOBS];
  int ktop[NJOBS];
  int K[NJOBS];
  long cum[NJOBS + 1];
};

__global__ void trans_pack_multi(TJobs J, long total)
{
  for (long u = (long)blockIdx.x * blockDim.x + threadIdx.x; u < total;
       u += (long)gridDim.x * blockDim.x) {
    int j = 0;
#pragma unroll
    for (int q = 1; q < NJOBS; q++) j += (u >= J.cum[q]) ? 1 : 0;
    long t8 = u - J.cum[j];
    int K = J.K[j], KT = K >> 5, ktop = J.ktop[j], ncols = J.ncols[j];
    const float* top = J.top[j];
    const float* bot = J.bot[j];
    int r = (int)(t8 & 15);
    int kg = (int)((t8 >> 4) & 3);
    long tile = t8 >> 6;
    int kt = (int)(tile % KT);
    int rt = (int)(tile / KT);
    int n = rt * 16 + r;
    int kb = kt * 32 + kg * 8;
    bf16x8 out;
#pragma unroll
    for (int jj = 0; jj < 8; jj++) {
      int k = kb + jj;
      float v = 0.f;
      if (n < ncols) {
        if (k < ktop) { if (top) v = top[(size_t)k * ncols + n]; }
        else if (bot) { v = bot[(size_t)(k - ktop) * ncols + n]; }
      }
      out[jj] = f2bs(v);
    }
    *(bf16x8*)(void*)(J.dst[j] + t8 * 8) = out;
  }
}

// Packed-transpose (single job) — used post-scan for WT_lo.
__global__ void trans_pack(const float* __restrict__ top, const float* __restrict__ bot,
                           bf16* __restrict__ dst, int ncols, long nElem8, int ktop, int K)
{
  int KT = K >> 5;
  for (long t8 = (long)blockIdx.x * blockDim.x + threadIdx.x; t8 < nElem8;
       t8 += (long)gridDim.x * blockDim.x) {
    int r = (int)(t8 & 15);
    int kg = (int)((t8 >> 4) & 3);
    long tile = t8 >> 6;
    int kt = (int)(tile % KT);
    int rt = (int)(tile / KT);
    int n = rt * 16 + r;
    int kb = kt * 32 + kg * 8;
    bf16x8 out;
#pragma unroll
    for (int j = 0; j < 8; j++) {
      int k = kb + j;
      float v = 0.f;
      if (n < ncols) {
        if (k < ktop) { if (top) v = top[(size_t)k * ncols + n]; }
        else if (bot) { v = bot[(size_t)(k - ktop) * ncols + n]; }
      }
      out[j] = f2bs(v);
    }
    *(bf16x8*)(void*)(dst + t8 * 8) = out;
  }
}

// enc (f32 row-major) -> enc_p (bf16 packed) AND enc_r (bf16 row-major)
__global__ void conv_pack(const float* __restrict__ src, bf16* __restrict__ dst,
                          bf16* __restrict__ dst_row, long nElem8)
{
  for (long t8 = (long)blockIdx.x * blockDim.x + threadIdx.x; t8 < nElem8;
       t8 += (long)gridDim.x * blockDim.x) {
    int r = (int)(t8 & 15);
    int kg = (int)((t8 >> 4) & 3);
    long tile = t8 >> 6;
    int kt = (int)(tile & 15);           // KT = 16 (K=512)
    int rt = (int)(tile >> 4);
    size_t rowoff = ((size_t)(rt * 16 + r)) * 512 + kt * 32 + kg * 8;
    const float* s = src + rowoff;
    bf16x8 out;
#pragma unroll
    for (int j = 0; j < 8; j++) out[j] = f2bs(s[j]);
    *(bf16x8*)(void*)(dst + t8 * 8) = out;
    *(bf16x8*)(void*)(dst_row + rowoff) = out;
  }
}

__global__ void bias_comb(const float* __restrict__ b_lstm, const float* __restrict__ b_s,
                          const float* __restrict__ b_g, const float* __restrict__ b_sa,
                          const float* __restrict__ b_Lh, const float* __restrict__ b_Lz,
                          const float* __restrict__ b_ih, const float* __restrict__ b_ic,
                          float* __restrict__ bg, float* __restrict__ ba,
                          float* __restrict__ bp, float* __restrict__ bi)
{
  int i = blockIdx.x * blockDim.x + threadIdx.x;
  if (i < 2560) bg[i] = (i < 2048) ? b_lstm[i] : b_s[i - 2048];
  if (i < 1024) ba[i] = (i < 512) ? b_g[i] : b_sa[i - 512];
  if (i < 512)  bp[i] = b_Lh[i] + b_Lz[i];
  if (i < 1024) bi[i] = (i < 512) ? b_ih[i] : b_ic[i - 512];
}

__global__ __launch_bounds__(128) void mean_enc(const float* __restrict__ enc,
                                                bf16* __restrict__ mb)
{
  int b = blockIdx.x, c = blockIdx.y * 128 + threadIdx.x;
  float s = 0.f;
  for (int l = 0; l < L_; l++) s += enc[((size_t)b * L_ + l) * 512 + c];
  mb[pidx(b, c, 512)] = f2b(s * (1.f / (float)L_));
}

__global__ void gather_x(const float* __restrict__ emb, const int* __restrict__ caps,
                         bf16* __restrict__ xbuf)
{
  int tb = blockIdx.x;          // t*128 + b
  int t = tb >> 7, b = tb & 127;
  int word = caps[b * 26 + t];
  int c0 = threadIdx.x * 8;
  const float* src = emb + (size_t)word * 512 + c0;
  bf16* dst = xbuf + pidx(tb, c0, 512);
  bf16x8 out;
#pragma unroll
  for (int j = 0; j < 8; j++) out[j] = f2bs(src[j]);
  *(bf16x8*)(void*)dst = out;
}

extern "C" void kernel_launch(void* const* d_in, const int* in_sizes, int n_in,
                              void* d_out, int out_size, void* d_ws, size_t ws_size,
                              hipStream_t stream)
{
  const float* enc      = (const float*)d_in[0];
  const int*   caps     = (const int*)d_in[1];
  const int*   clen     = (const int*)d_in[2];
  const float* emb      = (const float*)d_in[3];
  const float* W_ih     = (const float*)d_in[4];
  const float* W_hh     = (const float*)d_in[5];
  const float* b_lstm   = (const float*)d_in[6];
  const float* Wx_s     = (const float*)d_in[7];
  const float* Wh_s     = (const float*)d_in[8];
  const float* b_s      = (const float*)d_in[9];
  const float* W_v      = (const float*)d_in[10];
  const float* b_v      = (const float*)d_in[11];
  const float* W_g      = (const float*)d_in[12];
  const float* b_g      = (const float*)d_in[13];
  const float* W_s_att  = (const float*)d_in[14];
  const float* b_sa     = (const float*)d_in[15];
  const float* w_a      = (const float*)d_in[16];
  const float* W_init_h = (const float*)d_in[17];
  const float* b_init_h = (const float*)d_in[18];
  const float* W_init_c = (const float*)d_in[19];
  const float* b_init_c = (const float*)d_in[20];
  const float* W_Lh     = (const float*)d_in[21];
  const float* b_Lh     = (const float*)d_in[22];
  const float* W_Lz     = (const float*)d_in[23];
  const float* b_Lz     = (const float*)d_in[24];
  const float* W_Lo     = (const float*)d_in[25];
  const float* b_Lo     = (const float*)d_in[26];

  float* preds  = (float*)d_out;
  float* alphas = preds + (size_t)B_ * T_ * V_;
  float* betas  = alphas + (size_t)B_ * T_ * L_;

  char* ws = (char*)d_ws;
  size_t off = 0;
  auto alloc = [&](size_t bytes) -> void* {
    void* p = ws + off;
    off = (off + bytes + 255) & ~(size_t)255;
    return p;
  };
  bf16*  enc_p  = (bf16*)alloc((size_t)B_ * L_ * 512 * 2);   // overlay region later
  bf16*  enc_r  = (bf16*)alloc((size_t)B_ * L_ * 512 * 2);
  bf16*  attv_b = (bf16*)alloc((size_t)B_ * L_ * 512 * 2);
  bf16*  WT_gx  = (bf16*)alloc((size_t)2560 * 512 * 2);
  bf16*  WT_gh  = (bf16*)alloc((size_t)2560 * 512 * 2);
  bf16*  WT_a   = (bf16*)alloc((size_t)1024 * 1024 * 2);
  bf16*  WT_p   = (bf16*)alloc((size_t)512 * 1024 * 2);
  bf16*  WT_v   = (bf16*)alloc((size_t)512 * 512 * 2);
  bf16*  WT_i   = (bf16*)alloc((size_t)1024 * 512 * 2);
  float* bgx    = (float*)alloc(2560 * 4);
  float* bax    = (float*)alloc(1024 * 4);
  float* bpx    = (float*)alloc(512 * 4);
  float* bix    = (float*)alloc(1024 * 4);
  bf16*  mean_b = (bf16*)alloc(128 * 512 * 2);
  bf16*  xbuf   = (bf16*)alloc((size_t)T_ * 128 * 512 * 2);
  bf16*  hbuf   = (bf16*)alloc((size_t)(T_ + 1) * 128 * 512 * 2);
  bf16*  projA  = (bf16*)alloc((size_t)T_ * 128 * 1024 * 2);
  bf16*  agsw_b = (bf16*)alloc((size_t)T_ * 128 * 1024 * 2);
  float* cbuf   = (float*)alloc(128 * 512 * 4);
  unsigned* bar = (unsigned*)alloc(8192);
  if (off > ws_size) return;  // loud validation failure if ws too small

  // Overlays in the dead enc_p region (25,690,112 B):
  //   xg (16,384,000) | Aag (6,553,600) | alphas_raw (2,508,800) | betas_raw (12,800)
  bf16*  xg         = (bf16*)enc_p;               // written AFTER att_v GEMM
  bf16*  Aag        = (bf16*)((char*)enc_p + 16384000);
  float* alphas_raw = (float*)((char*)enc_p + 22937600);
  float* betas_raw  = (float*)((char*)enc_p + 25446400);
  // Overlays in the dead xg region (post-scan):
  bf16*  WT_lo = xg;                              // 10,485,760 B (transposed post-scan)
  bf16*  projb = (bf16*)((char*)xg + 10485760);   // 3,276,800 B

  hipMemsetAsync(bar, 0, 8192, stream);

  // ---- prep ----
  bias_comb<<<dim3(10), dim3(256), 0, stream>>>(b_lstm, b_s, b_g, b_sa, b_Lh, b_Lz,
                                                b_init_h, b_init_c, bgx, bax, bpx, bix);
  // fused 10-job packed transpose
  {
    TJobs J;
    auto set = [&](int j, const float* top, const float* bot, bf16* dst,
                   int ncols, int nrows, int ktop, int K) {
      J.top[j] = top; J.bot[j] = bot; J.dst[j] = dst;
      J.ncols[j] = ncols; J.ktop[j] = ktop; J.K[j] = K;
      J.cum[j + 1] = J.cum[j] + (long)nrows * K / 8;
    };
    J.cum[0] = 0;
    set(0, W_ih, nullptr, WT_gx, 2048, 2048, 512, 512);
    set(1, Wx_s, nullptr, WT_gx + (size_t)2048 * 512, 512, 512, 512, 512);
    set(2, W_hh, nullptr, WT_gh, 2048, 2048, 512, 512);
    set(3, Wh_s, nullptr, WT_gh + (size_t)2048 * 512, 512, 512, 512, 512);
    set(4, W_Lh, W_Lz, WT_p, 512, 512, 512, 1024);
    set(5, W_g, nullptr, WT_a, 512, 512, 512, 1024);
    set(6, nullptr, W_s_att, WT_a + (size_t)512 * 1024, 512, 512, 512, 1024);
    set(7, W_v, nullptr, WT_v, 512, 512, 512, 512);
    set(8, W_init_h, nullptr, WT_i, 512, 512, 512, 512);
    set(9, W_init_c, nullptr, WT_i + (size_t)512 * 512, 512, 512, 512, 512);
    long total = J.cum[NJOBS];
    int blocks = (int)((total + 255) / 256);
    if (blocks > 2048) blocks = 2048;
    trans_pack_multi<<<dim3(blocks), dim3(256), 0, stream>>>(J, total);
  }
  conv_pack<<<dim3(4096), dim3(256), 0, stream>>>(enc, enc_p, enc_r,
                                                  (long)B_ * L_ * 512 / 8);
  mean_enc<<<dim3(128, 4), dim3(128), 0, stream>>>(enc, mean_b);
  gather_x<<<dim3(T_ * 128), dim3(64), 0, stream>>>(emb, caps, xbuf);

  // h0 -> hbuf[0] (packed K=512), c0 -> cbuf (f32)
  gemm_pk<1, 1, EPI_INIT><<<dim3(8, 16), dim3(256), 0, stream>>>(
      mean_b, WT_i, bix, (void*)hbuf, nullptr, cbuf, 128, 1024, 512, 0, 1.f);
  // Ta = tanh(enc @ W_v + b_v)  (bf16 row-major) — LAST consumer of enc_p
  gemm_pk<8, 2, EPI_TANH><<<dim3(196, 4), dim3(256), 0, stream>>>(
      enc_p, WT_v, b_v, attv_b, nullptr, nullptr, B_ * L_, 512, 512, 512, 1.f);
  // xg = X_all @ [W_ih;Wx_s] + bias  (3200 x 2560 x 512, bf16, overlays enc_p)
  gemm_pk<8, 2, EPI_BF16><<<dim3(25, 20), dim3(256), 0, stream>>>(
      xbuf, WT_gx, bgx, xg, nullptr, nullptr, T_ * 128, 2560, 512, 2560, 1.f);

  // ---- persistent 25-step weight-stationary scan (8 groups x 32 blocks) ----
  scan_ws<<<dim3(256), dim3(256), 0, stream>>>(hbuf, WT_gh, xg, cbuf, Aag, projA, bar);

  // ---- batched attention pipeline ----
  // Tb = tanh([h|s]_all @ blockdiag(W_g, W_s_att) + [b_g|b_sa])  (bf16)
  gemm_pk<8, 2, EPI_TANH><<<dim3(25, 8), dim3(256), 0, stream>>>(
      Aag, WT_a, bax, agsw_b, nullptr, nullptr, T_ * 128, 1024, 1024, 1024, 1.f);
  // e-scores + softmax for all (b,t)
  e_batch<<<dim3(128, 25), dim3(256), 0, stream>>>(
      attv_b, agsw_b, w_a, clen, alphas, betas, alphas_raw, betas_raw);
  // WT_lo transpose (overlays dead xg) — must run after the scan
  {
    long n8 = (long)10240 * 512 / 8;
    trans_pack<<<dim3(2048), dim3(256), 0, stream>>>(W_Lo, nullptr, WT_lo,
                                                     10000, n8, 512, 512);
  }
  // ctx -> projA ctx-slots (reads enc ONCE, batched over all t)
  ctx_tail<<<dim3(128, 2), dim3(256), 0, stream>>>(alphas_raw, betas_raw, enc_r,
                                                   Aag, projA);
  // proj = x + [h|ctx] @ [W_Lh;W_Lz] + b   (3200 x 512 x 1024, packed out)
  gemm_pk<4, 2, EPI_PROJ><<<dim3(50, 4), dim3(256), 0, stream>>>(
      projA, WT_p, bpx, projb, xbuf, nullptr, T_ * 128, 512, 1024, 0, 1.f);
  // preds = proj @ W_Lo + b_Lo  (3200 x 10000 x 512)
  gemm_pk<8, 4, EPI_OUT><<<dim3(25, 40), dim3(256), 0, stream>>>(
      projb, WT_lo, b_Lo, preds, nullptr, nullptr, T_ * 128, V_, 512, 0, 1.f);
}

// Round 13
// 413.290 us; speedup vs baseline: 1.1309x; 1.1309x over previous
//
#include <hip/hip_runtime.h>
#include <hip/hip_bf16.h>
#include <cstdint>
#include <cstddef>

using bf16 = __hip_bfloat16;
typedef __attribute__((ext_vector_type(4))) float f32x4;
typedef __attribute__((ext_vector_type(8))) short bf16x8;

#define B_ 128
#define L_ 196
#define T_ 25
#define V_ 10000

__device__ __forceinline__ float b2f(short s) {
  unsigned u = ((unsigned)(unsigned short)s) << 16;
  return __uint_as_float(u);
}
__device__ __forceinline__ bf16 f2b(float f) { return __float2bfloat16(f); }
__device__ __forceinline__ short f2bs(float f) {
  return __builtin_bit_cast(short, __float2bfloat16(f));
}
__device__ __forceinline__ float sigf(float x) { return 1.f / (1.f + __expf(-x)); }
__device__ __forceinline__ float tanh_fast(float x) { return 1.f - 2.f / (1.f + __expf(2.f * x)); }

// sc1 write-through stores (push to L3); relaxed agent-scope loads for spin.
__device__ __forceinline__ void cst_u32(unsigned* p, unsigned v) {
  __hip_atomic_store(p, v, __ATOMIC_RELAXED, __HIP_MEMORY_SCOPE_AGENT);
}
__device__ __forceinline__ unsigned cld_u32(const unsigned* p) {
  return __hip_atomic_load((unsigned*)p, __ATOMIC_RELAXED, __HIP_MEMORY_SCOPE_AGENT);
}

// Fragment-packed layout: 16x32 tiles, tile-row-major; element (r,c) at
// (((r>>4)*KT + (c>>5))*64 + ((c&31)>>3)*16 + (r&15))*8 + (c&7).
__device__ __forceinline__ size_t pidx(int row, int col, int K) {
  int KT = K >> 5;
  return (((size_t)(row >> 4) * KT + (col >> 5)) * 64 +
          (size_t)(((col & 31) >> 3) * 16 + (row & 15))) * 8 + (col & 7);
}

__device__ __forceinline__ float wred_sum(float x) {
#pragma unroll
  for (int off = 32; off >= 1; off >>= 1) x += __shfl_xor(x, off, 64);
  return x;
}
__device__ __forceinline__ float wred_max(float x) {
#pragma unroll
  for (int off = 32; off >= 1; off >>= 1) x = fmaxf(x, __shfl_xor(x, off, 64));
  return x;
}

// ---- monotone single-counter group barrier (32 blocks per group) ----
// Last arrival's RMW IS the release; no second level, no gen store.
__device__ __forceinline__ void gbar_m(unsigned* bs, int mi, unsigned tgt) {
  asm volatile("s_waitcnt vmcnt(0)" ::: "memory");
  __syncthreads();
  if (threadIdx.x == 0) {
    unsigned* c = bs + mi * 64;       // 256B apart per group
    unsigned a = __hip_atomic_fetch_add(c, 1u, __ATOMIC_RELAXED,
                                        __HIP_MEMORY_SCOPE_AGENT);
    if (a + 1u < tgt) {
      while (cld_u32(c) < tgt) __builtin_amdgcn_s_sleep(1);
    }
  }
  __syncthreads();
}

// ---- persistent scan: weight-stationary, 256 blocks = 8 mi-groups x 32 di ----
// mi = blk&7 so a group's 32 blocks share the round-robin XCD slot (locality
// heuristic only; sc1 L3-push keeps it correct under any mapping).
__global__ __launch_bounds__(256) void scan_ws(
    bf16* __restrict__ hbuf,        // (T_+1) x (128x512 packed) h state
    const bf16* __restrict__ WT_gh, // 2560x512 packed (h-half weights)
    const bf16* __restrict__ xg,    // T_ x 128 x 2560 bf16 row-major: x@W + bias
    float* __restrict__ cbuf,       // 128x512 f32 cell state
    bf16* __restrict__ Aag,         // T_ x 128x1024 packed [h|s]  (post-scan)
    bf16* __restrict__ projA,       // T_ x 128x1024 packed [h|ctx] (post-scan)
    unsigned* __restrict__ bar)
{
  const int tid = threadIdx.x;
  const int wv = tid >> 6, lane = tid & 63;
  const int mi = blockIdx.x & 7;        // group: same XCD slot under round-robin
  const int di = blockIdx.x >> 3;       // 0..31 (cols di*16..+15)
  __shared__ f32x4 pacc[4][5][64];      // 20 KB split-K partials

  // ---- weight-stationary B fragments: bw[g][kk], kt = wv*4+kk ----
  bf16x8 bw[5][4];
#pragma unroll
  for (int g = 0; g < 5; g++)
#pragma unroll
    for (int kk = 0; kk < 4; kk++)
      bw[g][kk] = *(const bf16x8*)(const void*)(
          WT_gh + (size_t)(g * 32 + di) * 8192 + (size_t)(wv * 4 + kk) * 512 + lane * 8);

  const int el_r16 = lane & 15, el_r = lane >> 4;
  const int m_pw = mi * 16 + wv * 4 + el_r;
  const int d_pw = di * 16 + el_r16;
  const size_t qlo = pidx(m_pw, d_pw, 512);
  const size_t plo = pidx(m_pw, d_pw, 1024);
  const size_t phi = pidx(m_pw, 512 + d_pw, 1024);
  float* cp = cbuf + m_pw * 512 + d_pw;

  for (int tt = 0; tt < T_; ++tt) {
    const short* xr = (const short*)(const void*)(
        xg + (size_t)tt * (128 * 2560) + (size_t)m_pw * 2560 + d_pw);
    float xv0 = b2f(xr[0]);
    float xv1 = b2f(xr[512]);
    float xv2 = b2f(xr[1024]);
    float xv3 = b2f(xr[1536]);
    float xv4 = b2f(xr[2048]);
    const bf16* ap = hbuf + (size_t)tt * 65536 + (size_t)mi * 8192 + lane * 8;
    bf16x8 a0 = *(const bf16x8*)(const void*)(ap + (size_t)(wv * 4 + 0) * 512);
    bf16x8 a1 = *(const bf16x8*)(const void*)(ap + (size_t)(wv * 4 + 1) * 512);
    bf16x8 a2 = *(const bf16x8*)(const void*)(ap + (size_t)(wv * 4 + 2) * 512);
    bf16x8 a3 = *(const bf16x8*)(const void*)(ap + (size_t)(wv * 4 + 3) * 512);
    f32x4 acc[5];
#pragma unroll
    for (int g = 0; g < 5; g++) acc[g] = f32x4{0.f, 0.f, 0.f, 0.f};
#pragma unroll
    for (int g = 0; g < 5; g++) {
      acc[g] = __builtin_amdgcn_mfma_f32_16x16x32_bf16(a0, bw[g][0], acc[g], 0, 0, 0);
      acc[g] = __builtin_amdgcn_mfma_f32_16x16x32_bf16(a1, bw[g][1], acc[g], 0, 0, 0);
      acc[g] = __builtin_amdgcn_mfma_f32_16x16x32_bf16(a2, bw[g][2], acc[g], 0, 0, 0);
      acc[g] = __builtin_amdgcn_mfma_f32_16x16x32_bf16(a3, bw[g][3], acc[g], 0, 0, 0);
    }
#pragma unroll
    for (int g = 0; g < 5; g++) pacc[wv][g][lane] = acc[g];
    __syncthreads();
    float G0 = 0.f, G1 = 0.f, G2 = 0.f, G3 = 0.f, G4 = 0.f;
#pragma unroll
    for (int q = 0; q < 4; q++) {
      int sl = wv * 16 + el_r16;
      G0 += pacc[q][0][sl][el_r];
      G1 += pacc[q][1][sl][el_r];
      G2 += pacc[q][2][sl][el_r];
      G3 += pacc[q][3][sl][el_r];
      G4 += pacc[q][4][sl][el_r];
    }
    float cn = sigf(G1 + xv1) * (*cp) + sigf(G0 + xv0) * tanh_fast(G2 + xv2);
    float tcn = tanh_fast(cn);
    float hn = sigf(G3 + xv3) * tcn;
    float ss = sigf(G4 + xv4) * tcn;
    float hn1 = __shfl_down(hn, 1);
    float ss1 = __shfl_down(ss, 1);
    unsigned hp = 0, sp = 0;
    bool wr = !(el_r16 & 1);
    if (wr) {
      hp = (unsigned)(unsigned short)f2bs(hn) |
           ((unsigned)(unsigned short)f2bs(hn1) << 16);
      sp = (unsigned)(unsigned short)f2bs(ss) |
           ((unsigned)(unsigned short)f2bs(ss1) << 16);
      cst_u32((unsigned*)(void*)(hbuf + (size_t)(tt + 1) * 65536 + qlo), hp);
    }
    if (tt < T_ - 1) gbar_m(bar, mi, 32u * (unsigned)(tt + 1));
    *cp = cn;
    if (wr) {
      bf16* pA = projA + (size_t)tt * 131072;
      bf16* AagT = Aag + (size_t)tt * 131072;
      *(unsigned*)(void*)(pA + plo) = hp;
      *(unsigned*)(void*)(AagT + plo) = hp;
      *(unsigned*)(void*)(AagT + phi) = sp;
    }
  }
}

// ---- batched e-scores + softmax; grid (128, 25) ----
// attv and agsw store TANH of pre-activations:
//   tanh(a+b) = (Ta+Tb)/(1+Ta*Tb)   -> 1 rcp, no exp2.
__global__ __launch_bounds__(256) void e_batch(
    const bf16* __restrict__ attv, const bf16* __restrict__ agsw_all,
    const float* __restrict__ w_a, const int* __restrict__ clen,
    float* __restrict__ alphas, float* __restrict__ betas,
    float* __restrict__ alphas_raw, float* __restrict__ betas_raw)
{
  __shared__ float sh[200];
  __shared__ float red[8];
  int b = blockIdx.x, t = blockIdx.y;
  int tid = threadIdx.x, wv = tid >> 6, lane = tid & 63;
  const bf16* ag = agsw_all + ((size_t)t * 128 + b) * 1024;
  int a0 = lane * 8;
  float ag8[8], wa8[8], sw8[8];
  bf16x8 agv = *(const bf16x8*)(const void*)(ag + a0);
  bf16x8 swv = *(const bf16x8*)(const void*)(ag + 512 + a0);
#pragma unroll
  for (int j = 0; j < 8; j++) {
    ag8[j] = b2f(agv[j]);
    wa8[j] = w_a[a0 + j];
    sw8[j] = b2f(swv[j]);
  }
  for (int base = wv; base < 197; base += 16) {
    bf16x8 av[4];
#pragma unroll
    for (int q = 0; q < 4; q++) {
      int l = base + 4 * q;
      if (l < 196)
        av[q] = *(const bf16x8*)(const void*)(attv + ((size_t)(b * 196 + l)) * 512 + a0);
    }
#pragma unroll
    for (int q = 0; q < 4; q++) {
      int l = base + 4 * q;
      if (l > 196) continue;    // wave-uniform
      float part = 0.f;
      if (l < 196) {
#pragma unroll
        for (int j = 0; j < 8; j++) {
          float Ta = b2f(av[q][j]);
          float den = fmaf(Ta, ag8[j], 1.f);
          float num = Ta + ag8[j];
          part = fmaf(num * __builtin_amdgcn_rcpf(den), wa8[j], part);
        }
      } else {
#pragma unroll
        for (int j = 0; j < 8; j++) {
          float Ta = sw8[j];
          float den = fmaf(Ta, ag8[j], 1.f);
          float num = Ta + ag8[j];
          part = fmaf(num * __builtin_amdgcn_rcpf(den), wa8[j], part);
        }
      }
      part = wred_sum(part);
      if (lane == 0) sh[l] = part;
    }
  }
  __syncthreads();
  float v = (tid < 197) ? sh[tid] : -1e30f;
  float mx = wred_max(v);
  if (lane == 0) red[wv] = mx;
  __syncthreads();
  mx = fmaxf(fmaxf(red[0], red[1]), fmaxf(red[2], red[3]));
  float p = (tid < 197) ? __expf(v - mx) : 0.f;
  float sm = wred_sum(p);
  if (lane == 0) red[4 + wv] = sm;
  __syncthreads();
  float inv = 1.f / (red[4] + red[5] + red[6] + red[7]);
  float a = p * inv;
  int dec = clen[b] - 1; if (dec < 1) dec = 1;
  float act = (t < dec) ? 1.f : 0.f;
  if (tid < 196) {
    alphas[(size_t)b * (T_ * L_) + (size_t)t * L_ + tid] = a * act;
    alphas_raw[(size_t)b * (T_ * L_) + (size_t)t * L_ + tid] = a;
  }
  if (tid == 196) {
    betas[b * T_ + t] = a * act;
    betas_raw[b * T_ + t] = a;
  }
}

// ---- tail: ctx(b,t,:) = alpha_raw(b,t,:) @ enc(b) + beta*s ; write projA ctx ----
__global__ __launch_bounds__(256) void ctx_tail(
    const float* __restrict__ alphas_raw, const float* __restrict__ betas_raw,
    const bf16* __restrict__ enc_r, const bf16* __restrict__ Aag,
    bf16* __restrict__ projA)
{
  int b = blockIdx.x, cs = blockIdx.y, tid = threadIdx.x;
  __shared__ float al[T_ * 200];
  for (int i = tid; i < T_ * 196; i += 256) {
    al[(i / 196) * 200 + (i % 196)] = alphas_raw[(size_t)b * (T_ * 196) + i];
  }
  __syncthreads();
  int ch = cs * 256 + tid;
  float acc[T_];
#pragma unroll
  for (int t = 0; t < T_; t++) acc[t] = 0.f;
  const short* ep = (const short*)(const void*)(enc_r) + (size_t)b * 196 * 512 + ch;
#pragma unroll 4
  for (int l = 0; l < 196; l++) {
    float e = b2f(ep[(size_t)l * 512]);
#pragma unroll
    for (int t = 0; t < T_; t++) acc[t] += al[t * 200 + l] * e;
  }
#pragma unroll
  for (int t = 0; t < T_; t++) {
    float beta = betas_raw[b * T_ + t];
    float sv = b2f(((const short*)(const void*)Aag)[(size_t)t * 131072 + pidx(b, 512 + ch, 1024)]);
    projA[(size_t)t * 131072 + pidx(b, 512 + ch, 1024)] = f2b(acc[t] + beta * sv);
  }
}

enum { EPI_F32 = 0, EPI_BF16 = 1, EPI_INIT = 2, EPI_PROJ = 3, EPI_OUT = 4, EPI_TANH = 5 };

// C = A (MxK packed) @ BT^T (BT: NxK packed), + bias.
template<int MFRAG, int NFRAG, int EPI>
__global__ __launch_bounds__(256) void gemm_pk(
    const bf16* __restrict__ A, const bf16* __restrict__ BT,
    const float* __restrict__ bias, void* __restrict__ Cp,
    const bf16* __restrict__ auxA, float* __restrict__ auxB,
    int M, int N, int K, int ldc, float oscale)
{
  const int lane = threadIdx.x & 63;
  const int wv = threadIdx.x >> 6;
  const int r16 = lane & 15;
  const int kg = lane >> 4;
  const int m0 = blockIdx.x * (MFRAG * 16);
  const int n0 = blockIdx.y * (NFRAG * 64) + wv * (NFRAG * 16);
  const int KT = K >> 5;

  f32x4 acc[MFRAG][NFRAG];
#pragma unroll
  for (int i = 0; i < MFRAG; i++)
#pragma unroll
    for (int j = 0; j < NFRAG; j++) acc[i][j] = f32x4{0.f, 0.f, 0.f, 0.f};

  const bf16* ap = A + (size_t)(m0 >> 4) * KT * 512 + lane * 8;
  const bf16* bp = BT + (size_t)(n0 >> 4) * KT * 512 + lane * 8;

#pragma unroll 4
  for (int kt = 0; kt < KT; kt++) {
    bf16x8 af[MFRAG], bfr[NFRAG];
#pragma unroll
    for (int i = 0; i < MFRAG; i++)
      af[i] = *(const bf16x8*)(const void*)(ap + ((size_t)i * KT + kt) * 512);
#pragma unroll
    for (int j = 0; j < NFRAG; j++)
      bfr[j] = *(const bf16x8*)(const void*)(bp + ((size_t)j * KT + kt) * 512);
#pragma unroll
    for (int i = 0; i < MFRAG; i++)
#pragma unroll
      for (int j = 0; j < NFRAG; j++)
        acc[i][j] = __builtin_amdgcn_mfma_f32_16x16x32_bf16(af[i], bfr[j], acc[i][j], 0, 0, 0);
  }

#pragma unroll
  for (int i = 0; i < MFRAG; i++)
#pragma unroll
    for (int j = 0; j < NFRAG; j++)
#pragma unroll
      for (int r = 0; r < 4; r++) {
        int m = m0 + i * 16 + kg * 4 + r;
        int n = n0 + j * 16 + r16;
        if (n >= N) continue;
        float v = acc[i][j][r] + bias[n];
        if constexpr (EPI == EPI_F32) {
          ((float*)Cp)[(size_t)m * ldc + n] = v * oscale;
        } else if constexpr (EPI == EPI_BF16) {
          ((bf16*)Cp)[(size_t)m * ldc + n] = f2b(v * oscale);
        } else if constexpr (EPI == EPI_TANH) {
          ((bf16*)Cp)[(size_t)m * ldc + n] = f2b(tanh_fast(v));
        } else if constexpr (EPI == EPI_INIT) {
          float tv = tanhf(v);
          if (n < 512) ((bf16*)Cp)[pidx(m, n, 512)] = f2b(tv);   // h0 -> hbuf[0]
          else auxB[(size_t)m * 512 + (n - 512)] = tv;           // c0 (f32)
        } else if constexpr (EPI == EPI_PROJ) {
          v += b2f(((const short*)auxA)[pidx(m, n, 512)]);       // + x (xbuf)
          ((bf16*)Cp)[pidx(m, n, 512)] = f2b(v);
        } else {  // EPI_OUT: preds[b, t, n], row = t*128+b
          int t = m >> 7, b = m & 127;
          ((float*)Cp)[(size_t)b * (T_ * V_) + (size_t)t * V_ + n] = v;
        }
      }
}

// ---- fused multi-job packed-transpose ----
#define NJOBS 10
struct TJobs {
  const float* top[NJOBS];
  const float* bot[NJOBS];
  bf16* dst[NJOBS];
  int ncols[NJOBS];
  int ktop[NJOBS];
  int K[NJOBS];
  long cum[NJOBS + 1];
};

__global__ void trans_pack_multi(TJobs J, long total)
{
  for (long u = (long)blockIdx.x * blockDim.x + threadIdx.x; u < total;
       u += (long)gridDim.x * blockDim.x) {
    int j = 0;
#pragma unroll
    for (int q = 1; q < NJOBS; q++) j += (u >= J.cum[q]) ? 1 : 0;
    long t8 = u - J.cum[j];
    int K = J.K[j], KT = K >> 5, ktop = J.ktop[j], ncols = J.ncols[j];
    const float* top = J.top[j];
    const float* bot = J.bot[j];
    int r = (int)(t8 & 15);
    int kg = (int)((t8 >> 4) & 3);
    long tile = t8 >> 6;
    int kt = (int)(tile % KT);
    int rt = (int)(tile / KT);
    int n = rt * 16 + r;
    int kb = kt * 32 + kg * 8;
    bf16x8 out;
#pragma unroll
    for (int jj = 0; jj < 8; jj++) {
      int k = kb + jj;
      float v = 0.f;
      if (n < ncols) {
        if (k < ktop) { if (top) v = top[(size_t)k * ncols + n]; }
        else if (bot) { v = bot[(size_t)(k - ktop) * ncols + n]; }
      }
      out[jj] = f2bs(v);
    }
    *(bf16x8*)(void*)(J.dst[j] + t8 * 8) = out;
  }
}

// Packed-transpose (single job) — used post-scan for WT_lo.
__global__ void trans_pack(const float* __restrict__ top, const float* __restrict__ bot,
                           bf16* __restrict__ dst, int ncols, long nElem8, int ktop, int K)
{
  int KT = K >> 5;
  for (long t8 = (long)blockIdx.x * blockDim.x + threadIdx.x; t8 < nElem8;
       t8 += (long)gridDim.x * blockDim.x) {
    int r = (int)(t8 & 15);
    int kg = (int)((t8 >> 4) & 3);
    long tile = t8 >> 6;
    int kt = (int)(tile % KT);
    int rt = (int)(tile / KT);
    int n = rt * 16 + r;
    int kb = kt * 32 + kg * 8;
    bf16x8 out;
#pragma unroll
    for (int j = 0; j < 8; j++) {
      int k = kb + j;
      float v = 0.f;
      if (n < ncols) {
        if (k < ktop) { if (top) v = top[(size_t)k * ncols + n]; }
        else if (bot) { v = bot[(size_t)(k - ktop) * ncols + n]; }
      }
      out[j] = f2bs(v);
    }
    *(bf16x8*)(void*)(dst + t8 * 8) = out;
  }
}

// enc (f32 row-major) -> enc_p (bf16 packed) AND enc_r (bf16 row-major)
__global__ void conv_pack(const float* __restrict__ src, bf16* __restrict__ dst,
                          bf16* __restrict__ dst_row, long nElem8)
{
  for (long t8 = (long)blockIdx.x * blockDim.x + threadIdx.x; t8 < nElem8;
       t8 += (long)gridDim.x * blockDim.x) {
    int r = (int)(t8 & 15);
    int kg = (int)((t8 >> 4) & 3);
    long tile = t8 >> 6;
    int kt = (int)(tile & 15);           // KT = 16 (K=512)
    int rt = (int)(tile >> 4);
    size_t rowoff = ((size_t)(rt * 16 + r)) * 512 + kt * 32 + kg * 8;
    const float* s = src + rowoff;
    bf16x8 out;
#pragma unroll
    for (int j = 0; j < 8; j++) out[j] = f2bs(s[j]);
    *(bf16x8*)(void*)(dst + t8 * 8) = out;
    *(bf16x8*)(void*)(dst_row + rowoff) = out;
  }
}

__global__ void bias_comb(const float* __restrict__ b_lstm, const float* __restrict__ b_s,
                          const float* __restrict__ b_g, const float* __restrict__ b_sa,
                          const float* __restrict__ b_Lh, const float* __restrict__ b_Lz,
                          const float* __restrict__ b_ih, const float* __restrict__ b_ic,
                          float* __restrict__ bg, float* __restrict__ ba,
                          float* __restrict__ bp, float* __restrict__ bi)
{
  int i = blockIdx.x * blockDim.x + threadIdx.x;
  if (i < 2560) bg[i] = (i < 2048) ? b_lstm[i] : b_s[i - 2048];
  if (i < 1024) ba[i] = (i < 512) ? b_g[i] : b_sa[i - 512];
  if (i < 512)  bp[i] = b_Lh[i] + b_Lz[i];
  if (i < 1024) bi[i] = (i < 512) ? b_ih[i] : b_ic[i - 512];
}

__global__ __launch_bounds__(128) void mean_enc(const float* __restrict__ enc,
                                                bf16* __restrict__ mb)
{
  int b = blockIdx.x, c = blockIdx.y * 128 + threadIdx.x;
  float s = 0.f;
  for (int l = 0; l < L_; l++) s += enc[((size_t)b * L_ + l) * 512 + c];
  mb[pidx(b, c, 512)] = f2b(s * (1.f / (float)L_));
}

__global__ void gather_x(const float* __restrict__ emb, const int* __restrict__ caps,
                         bf16* __restrict__ xbuf)
{
  int tb = blockIdx.x;          // t*128 + b
  int t = tb >> 7, b = tb & 127;
  int word = caps[b * 26 + t];
  int c0 = threadIdx.x * 8;
  const float* src = emb + (size_t)word * 512 + c0;
  bf16* dst = xbuf + pidx(tb, c0, 512);
  bf16x8 out;
#pragma unroll
  for (int j = 0; j < 8; j++) out[j] = f2bs(src[j]);
  *(bf16x8*)(void*)dst = out;
}

extern "C" void kernel_launch(void* const* d_in, const int* in_sizes, int n_in,
                              void* d_out, int out_size, void* d_ws, size_t ws_size,
                              hipStream_t stream)
{
  const float* enc      = (const float*)d_in[0];
  const int*   caps     = (const int*)d_in[1];
  const int*   clen     = (const int*)d_in[2];
  const float* emb      = (const float*)d_in[3];
  const float* W_ih     = (const float*)d_in[4];
  const float* W_hh     = (const float*)d_in[5];
  const float* b_lstm   = (const float*)d_in[6];
  const float* Wx_s     = (const float*)d_in[7];
  const float* Wh_s     = (const float*)d_in[8];
  const float* b_s      = (const float*)d_in[9];
  const float* W_v      = (const float*)d_in[10];
  const float* b_v      = (const float*)d_in[11];
  const float* W_g      = (const float*)d_in[12];
  const float* b_g      = (const float*)d_in[13];
  const float* W_s_att  = (const float*)d_in[14];
  const float* b_sa     = (const float*)d_in[15];
  const float* w_a      = (const float*)d_in[16];
  const float* W_init_h = (const float*)d_in[17];
  const float* b_init_h = (const float*)d_in[18];
  const float* W_init_c = (const float*)d_in[19];
  const float* b_init_c = (const float*)d_in[20];
  const float* W_Lh     = (const float*)d_in[21];
  const float* b_Lh     = (const float*)d_in[22];
  const float* W_Lz     = (const float*)d_in[23];
  const float* b_Lz     = (const float*)d_in[24];
  const float* W_Lo     = (const float*)d_in[25];
  const float* b_Lo     = (const float*)d_in[26];

  float* preds  = (float*)d_out;
  float* alphas = preds + (size_t)B_ * T_ * V_;
  float* betas  = alphas + (size_t)B_ * T_ * L_;

  char* ws = (char*)d_ws;
  size_t off = 0;
  auto alloc = [&](size_t bytes) -> void* {
    void* p = ws + off;
    off = (off + bytes + 255) & ~(size_t)255;
    return p;
  };
  bf16*  enc_p  = (bf16*)alloc((size_t)B_ * L_ * 512 * 2);   // overlay region later
  bf16*  enc_r  = (bf16*)alloc((size_t)B_ * L_ * 512 * 2);
  bf16*  attv_b = (bf16*)alloc((size_t)B_ * L_ * 512 * 2);
  bf16*  WT_gx  = (bf16*)alloc((size_t)2560 * 512 * 2);
  bf16*  WT_gh  = (bf16*)alloc((size_t)2560 * 512 * 2);
  bf16*  WT_a   = (bf16*)alloc((size_t)1024 * 1024 * 2);
  bf16*  WT_p   = (bf16*)alloc((size_t)512 * 1024 * 2);
  bf16*  WT_v   = (bf16*)alloc((size_t)512 * 512 * 2);
  bf16*  WT_i   = (bf16*)alloc((size_t)1024 * 512 * 2);
  float* bgx    = (float*)alloc(2560 * 4);
  float* bax    = (float*)alloc(1024 * 4);
  float* bpx    = (float*)alloc(512 * 4);
  float* bix    = (float*)alloc(1024 * 4);
  bf16*  mean_b = (bf16*)alloc(128 * 512 * 2);
  bf16*  xbuf   = (bf16*)alloc((size_t)T_ * 128 * 512 * 2);
  bf16*  hbuf   = (bf16*)alloc((size_t)(T_ + 1) * 128 * 512 * 2);
  bf16*  projA  = (bf16*)alloc((size_t)T_ * 128 * 1024 * 2);
  bf16*  agsw_b = (bf16*)alloc((size_t)T_ * 128 * 1024 * 2);
  float* cbuf   = (float*)alloc(128 * 512 * 4);
  unsigned* bar = (unsigned*)alloc(8192);
  if (off > ws_size) return;  // loud validation failure if ws too small

  // Overlays in the dead enc_p region (25,690,112 B):
  //   xg (16,384,000) | Aag (6,553,600) | alphas_raw (2,508,800) | betas_raw (12,800)
  bf16*  xg         = (bf16*)enc_p;               // written AFTER att_v GEMM
  bf16*  Aag        = (bf16*)((char*)enc_p + 16384000);
  float* alphas_raw = (float*)((char*)enc_p + 22937600);
  float* betas_raw  = (float*)((char*)enc_p + 25446400);
  // Overlays in the dead xg region (post-scan):
  bf16*  WT_lo = xg;                              // 10,485,760 B (transposed post-scan)
  bf16*  projb = (bf16*)((char*)xg + 10485760);   // 3,276,800 B

  hipMemsetAsync(bar, 0, 8192, stream);

  // ---- prep ----
  bias_comb<<<dim3(10), dim3(256), 0, stream>>>(b_lstm, b_s, b_g, b_sa, b_Lh, b_Lz,
                                                b_init_h, b_init_c, bgx, bax, bpx, bix);
  // fused 10-job packed transpose
  {
    TJobs J;
    auto set = [&](int j, const float* top, const float* bot, bf16* dst,
                   int ncols, int nrows, int ktop, int K) {
      J.top[j] = top; J.bot[j] = bot; J.dst[j] = dst;
      J.ncols[j] = ncols; J.ktop[j] = ktop; J.K[j] = K;
      J.cum[j + 1] = J.cum[j] + (long)nrows * K / 8;
    };
    J.cum[0] = 0;
    set(0, W_ih, nullptr, WT_gx, 2048, 2048, 512, 512);
    set(1, Wx_s, nullptr, WT_gx + (size_t)2048 * 512, 512, 512, 512, 512);
    set(2, W_hh, nullptr, WT_gh, 2048, 2048, 512, 512);
    set(3, Wh_s, nullptr, WT_gh + (size_t)2048 * 512, 512, 512, 512, 512);
    set(4, W_Lh, W_Lz, WT_p, 512, 512, 512, 1024);
    set(5, W_g, nullptr, WT_a, 512, 512, 512, 1024);
    set(6, nullptr, W_s_att, WT_a + (size_t)512 * 1024, 512, 512, 512, 1024);
    set(7, W_v, nullptr, WT_v, 512, 512, 512, 512);
    set(8, W_init_h, nullptr, WT_i, 512, 512, 512, 512);
    set(9, W_init_c, nullptr, WT_i + (size_t)512 * 512, 512, 512, 512, 512);
    long total = J.cum[NJOBS];
    int blocks = (int)((total + 255) / 256);
    if (blocks > 2048) blocks = 2048;
    trans_pack_multi<<<dim3(blocks), dim3(256), 0, stream>>>(J, total);
  }
  conv_pack<<<dim3(4096), dim3(256), 0, stream>>>(enc, enc_p, enc_r,
                                                  (long)B_ * L_ * 512 / 8);
  mean_enc<<<dim3(128, 4), dim3(128), 0, stream>>>(enc, mean_b);
  gather_x<<<dim3(T_ * 128), dim3(64), 0, stream>>>(emb, caps, xbuf);

  // h0 -> hbuf[0] (packed K=512), c0 -> cbuf (f32)
  gemm_pk<1, 1, EPI_INIT><<<dim3(8, 16), dim3(256), 0, stream>>>(
      mean_b, WT_i, bix, (void*)hbuf, nullptr, cbuf, 128, 1024, 512, 0, 1.f);
  // Ta = tanh(enc @ W_v + b_v)  (bf16 row-major) — LAST consumer of enc_p
  gemm_pk<4, 2, EPI_TANH><<<dim3(392, 4), dim3(256), 0, stream>>>(
      enc_p, WT_v, b_v, attv_b, nullptr, nullptr, B_ * L_, 512, 512, 512, 1.f);
  // xg = X_all @ [W_ih;Wx_s] + bias  (3200 x 2560 x 512, bf16, overlays enc_p)
  gemm_pk<4, 2, EPI_BF16><<<dim3(50, 20), dim3(256), 0, stream>>>(
      xbuf, WT_gx, bgx, xg, nullptr, nullptr, T_ * 128, 2560, 512, 2560, 1.f);

  // ---- persistent 25-step weight-stationary scan (8 groups x 32 blocks) ----
  scan_ws<<<dim3(256), dim3(256), 0, stream>>>(hbuf, WT_gh, xg, cbuf, Aag, projA, bar);

  // ---- batched attention pipeline ----
  // Tb = tanh([h|s]_all @ blockdiag(W_g, W_s_att) + [b_g|b_sa])  (bf16)
  gemm_pk<4, 2, EPI_TANH><<<dim3(50, 8), dim3(256), 0, stream>>>(
      Aag, WT_a, bax, agsw_b, nullptr, nullptr, T_ * 128, 1024, 1024, 1024, 1.f);
  // e-scores + softmax for all (b,t)
  e_batch<<<dim3(128, 25), dim3(256), 0, stream>>>(
      attv_b, agsw_b, w_a, clen, alphas, betas, alphas_raw, betas_raw);
  // WT_lo transpose (overlays dead xg) — must run after the scan
  {
    long n8 = (long)10240 * 512 / 8;
    trans_pack<<<dim3(2048), dim3(256), 0, stream>>>(W_Lo, nullptr, WT_lo,
                                                     10000, n8, 512, 512);
  }
  // ctx -> projA ctx-slots (reads enc ONCE, batched over all t)
  ctx_tail<<<dim3(128, 2), dim3(256), 0, stream>>>(alphas_raw, betas_raw, enc_r,
                                                   Aag, projA);
  // proj = x + [h|ctx] @ [W_Lh;W_Lz] + b   (3200 x 512 x 1024, packed out)
  gemm_pk<4, 2, EPI_PROJ><<<dim3(50, 4), dim3(256), 0, stream>>>(
      projA, WT_p, bpx, projb, xbuf, nullptr, T_ * 128, 512, 1024, 0, 1.f);
  // preds = proj @ W_Lo + b_Lo  (3200 x 10000 x 512)
  gemm_pk<4, 4, EPI_OUT><<<dim3(50, 40), dim3(256), 0, stream>>>(
      projb, WT_lo, b_Lo, preds, nullptr, nullptr, T_ * 128, V_, 512, 0, 1.f);
}

// Round 14
// 392.777 us; speedup vs baseline: 1.1899x; 1.0522x over previous
//
#include <hip/hip_runtime.h>
#include <hip/hip_bf16.h>
#include <cstdint>
#include <cstddef>

using bf16 = __hip_bfloat16;
typedef __attribute__((ext_vector_type(4))) float f32x4;
typedef __attribute__((ext_vector_type(8))) short bf16x8;

#define B_ 128
#define L_ 196
#define T_ 25
#define V_ 10000
#define ESCL 2.885390081777927f   // 2*log2(e): tanh(z) = 1 - 2/(1+exp2(z*ESCL))

__device__ __forceinline__ float b2f(short s) {
  unsigned u = ((unsigned)(unsigned short)s) << 16;
  return __uint_as_float(u);
}
__device__ __forceinline__ bf16 f2b(float f) { return __float2bfloat16(f); }
__device__ __forceinline__ short f2bs(float f) {
  return __builtin_bit_cast(short, __float2bfloat16(f));
}
__device__ __forceinline__ float sigf(float x) { return 1.f / (1.f + __expf(-x)); }
__device__ __forceinline__ float tanh_fast(float x) { return 1.f - 2.f / (1.f + __expf(2.f * x)); }

// sc1 write-through stores (push to L3); relaxed agent-scope loads for spin.
__device__ __forceinline__ void cst_u32(unsigned* p, unsigned v) {
  __hip_atomic_store(p, v, __ATOMIC_RELAXED, __HIP_MEMORY_SCOPE_AGENT);
}
__device__ __forceinline__ unsigned cld_u32(const unsigned* p) {
  return __hip_atomic_load((unsigned*)p, __ATOMIC_RELAXED, __HIP_MEMORY_SCOPE_AGENT);
}

// Fragment-packed layout: 16x32 tiles, tile-row-major; element (r,c) at
// (((r>>4)*KT + (c>>5))*64 + ((c&31)>>3)*16 + (r&15))*8 + (c&7).
__device__ __forceinline__ size_t pidx(int row, int col, int K) {
  int KT = K >> 5;
  return (((size_t)(row >> 4) * KT + (col >> 5)) * 64 +
          (size_t)(((col & 31) >> 3) * 16 + (row & 15))) * 8 + (col & 7);
}

__device__ __forceinline__ float wred_sum(float x) {
#pragma unroll
  for (int off = 32; off >= 1; off >>= 1) x += __shfl_xor(x, off, 64);
  return x;
}
__device__ __forceinline__ float wred_max(float x) {
#pragma unroll
  for (int off = 32; off >= 1; off >>= 1) x = fmaxf(x, __shfl_xor(x, off, 64));
  return x;
}

// ---- monotone single-counter group barrier (32 blocks per group) ----
__device__ __forceinline__ void gbar_m(unsigned* bs, int mi, unsigned tgt) {
  asm volatile("s_waitcnt vmcnt(0)" ::: "memory");
  __syncthreads();
  if (threadIdx.x == 0) {
    unsigned* c = bs + mi * 64;       // 256B apart per group
    unsigned a = __hip_atomic_fetch_add(c, 1u, __ATOMIC_RELAXED,
                                        __HIP_MEMORY_SCOPE_AGENT);
    if (a + 1u < tgt) {
      while (cld_u32(c) < tgt) __builtin_amdgcn_s_sleep(1);
    }
  }
  __syncthreads();
}

// ---- persistent scan: weight-stationary, 256 blocks = 8 mi-groups x 32 di ----
__global__ __launch_bounds__(256) void scan_ws(
    bf16* __restrict__ hbuf,        // (T_+1) x (128x512 packed) h state
    const bf16* __restrict__ WT_gh, // 2560x512 packed (h-half weights)
    const bf16* __restrict__ xg,    // T_ x 128 x 2560 bf16 row-major: x@W + bias
    float* __restrict__ cbuf,       // 128x512 f32 cell state
    bf16* __restrict__ Aag,         // T_ x 128x1024 packed [h|s]  (post-scan)
    bf16* __restrict__ projA,       // T_ x 128x1024 packed [h|ctx] (post-scan)
    unsigned* __restrict__ bar)
{
  const int tid = threadIdx.x;
  const int wv = tid >> 6, lane = tid & 63;
  const int mi = blockIdx.x & 7;        // group: same XCD slot under round-robin
  const int di = blockIdx.x >> 3;       // 0..31 (cols di*16..+15)
  __shared__ f32x4 pacc[4][5][64];      // 20 KB split-K partials

  // ---- weight-stationary B fragments: bw[g][kk], kt = wv*4+kk ----
  bf16x8 bw[5][4];
#pragma unroll
  for (int g = 0; g < 5; g++)
#pragma unroll
    for (int kk = 0; kk < 4; kk++)
      bw[g][kk] = *(const bf16x8*)(const void*)(
          WT_gh + (size_t)(g * 32 + di) * 8192 + (size_t)(wv * 4 + kk) * 512 + lane * 8);

  const int el_r16 = lane & 15, el_r = lane >> 4;
  const int m_pw = mi * 16 + wv * 4 + el_r;
  const int d_pw = di * 16 + el_r16;
  const size_t qlo = pidx(m_pw, d_pw, 512);
  const size_t plo = pidx(m_pw, d_pw, 1024);
  const size_t phi = pidx(m_pw, 512 + d_pw, 1024);
  float* cp = cbuf + m_pw * 512 + d_pw;

  for (int tt = 0; tt < T_; ++tt) {
    const short* xr = (const short*)(const void*)(
        xg + (size_t)tt * (128 * 2560) + (size_t)m_pw * 2560 + d_pw);
    float xv0 = b2f(xr[0]);
    float xv1 = b2f(xr[512]);
    float xv2 = b2f(xr[1024]);
    float xv3 = b2f(xr[1536]);
    float xv4 = b2f(xr[2048]);
    const bf16* ap = hbuf + (size_t)tt * 65536 + (size_t)mi * 8192 + lane * 8;
    bf16x8 a0 = *(const bf16x8*)(const void*)(ap + (size_t)(wv * 4 + 0) * 512);
    bf16x8 a1 = *(const bf16x8*)(const void*)(ap + (size_t)(wv * 4 + 1) * 512);
    bf16x8 a2 = *(const bf16x8*)(const void*)(ap + (size_t)(wv * 4 + 2) * 512);
    bf16x8 a3 = *(const bf16x8*)(const void*)(ap + (size_t)(wv * 4 + 3) * 512);
    f32x4 acc[5];
#pragma unroll
    for (int g = 0; g < 5; g++) acc[g] = f32x4{0.f, 0.f, 0.f, 0.f};
#pragma unroll
    for (int g = 0; g < 5; g++) {
      acc[g] = __builtin_amdgcn_mfma_f32_16x16x32_bf16(a0, bw[g][0], acc[g], 0, 0, 0);
      acc[g] = __builtin_amdgcn_mfma_f32_16x16x32_bf16(a1, bw[g][1], acc[g], 0, 0, 0);
      acc[g] = __builtin_amdgcn_mfma_f32_16x16x32_bf16(a2, bw[g][2], acc[g], 0, 0, 0);
      acc[g] = __builtin_amdgcn_mfma_f32_16x16x32_bf16(a3, bw[g][3], acc[g], 0, 0, 0);
    }
#pragma unroll
    for (int g = 0; g < 5; g++) pacc[wv][g][lane] = acc[g];
    __syncthreads();
    float G0 = 0.f, G1 = 0.f, G2 = 0.f, G3 = 0.f, G4 = 0.f;
#pragma unroll
    for (int q = 0; q < 4; q++) {
      int sl = wv * 16 + el_r16;
      G0 += pacc[q][0][sl][el_r];
      G1 += pacc[q][1][sl][el_r];
      G2 += pacc[q][2][sl][el_r];
      G3 += pacc[q][3][sl][el_r];
      G4 += pacc[q][4][sl][el_r];
    }
    float cn = sigf(G1 + xv1) * (*cp) + sigf(G0 + xv0) * tanh_fast(G2 + xv2);
    float tcn = tanh_fast(cn);
    float hn = sigf(G3 + xv3) * tcn;
    float ss = sigf(G4 + xv4) * tcn;
    float hn1 = __shfl_down(hn, 1);
    float ss1 = __shfl_down(ss, 1);
    unsigned hp = 0, sp = 0;
    bool wr = !(el_r16 & 1);
    if (wr) {
      hp = (unsigned)(unsigned short)f2bs(hn) |
           ((unsigned)(unsigned short)f2bs(hn1) << 16);
      sp = (unsigned)(unsigned short)f2bs(ss) |
           ((unsigned)(unsigned short)f2bs(ss1) << 16);
      cst_u32((unsigned*)(void*)(hbuf + (size_t)(tt + 1) * 65536 + qlo), hp);
    }
    if (tt < T_ - 1) gbar_m(bar, mi, 32u * (unsigned)(tt + 1));
    *cp = cn;
    if (wr) {
      bf16* pA = projA + (size_t)tt * 131072;
      bf16* AagT = Aag + (size_t)tt * 131072;
      *(unsigned*)(void*)(pA + plo) = hp;
      *(unsigned*)(void*)(AagT + plo) = hp;
      *(unsigned*)(void*)(AagT + phi) = sp;
    }
  }
}

// ---- batched e-scores + softmax; grid (128, 25) ----
// attv/agsw store E = exp2(ESCL * preact), so tanh(a+g) = 1 - 2/(1+Ea*Eb) and
//   e = Wsum - 2 * sum_d wa_d * rcp(1 + Ea*Eb)
__global__ __launch_bounds__(256) void e_batch(
    const bf16* __restrict__ attv, const bf16* __restrict__ agsw_all,
    const float* __restrict__ w_a, const int* __restrict__ clen,
    float* __restrict__ alphas, float* __restrict__ betas,
    float* __restrict__ alphas_raw, float* __restrict__ betas_raw)
{
  __shared__ float sh[200];
  __shared__ float red[8];
  int b = blockIdx.x, t = blockIdx.y;
  int tid = threadIdx.x, wv = tid >> 6, lane = tid & 63;
  const bf16* ag = agsw_all + ((size_t)t * 128 + b) * 1024;
  int a0 = lane * 8;
  float ag8[8], wa8[8], sw8[8];
  float wsum = 0.f;
  bf16x8 agv = *(const bf16x8*)(const void*)(ag + a0);
  bf16x8 swv = *(const bf16x8*)(const void*)(ag + 512 + a0);
#pragma unroll
  for (int j = 0; j < 8; j++) {
    ag8[j] = b2f(agv[j]);         // Eb
    wa8[j] = w_a[a0 + j];
    sw8[j] = b2f(swv[j]);         // Es
    wsum += wa8[j];
  }
  wsum = wred_sum(wsum);
  // main rows l < 196
  for (int base = wv; base < 196; base += 16) {
    bf16x8 av[4];
#pragma unroll
    for (int q = 0; q < 4; q++) {
      int l = base + 4 * q;
      if (l < 196)
        av[q] = *(const bf16x8*)(const void*)(attv + ((size_t)(b * 196 + l)) * 512 + a0);
    }
#pragma unroll
    for (int q = 0; q < 4; q++) {
      int l = base + 4 * q;
      if (l >= 196) continue;    // wave-uniform (only final iteration)
      float part = 0.f;
#pragma unroll
      for (int j = 0; j < 8; j++) {
        float P = b2f(av[q][j]) * ag8[j];
        part = fmaf(wa8[j], __builtin_amdgcn_rcpf(1.f + P), part);
      }
      part = wred_sum(part);
      if (lane == 0) sh[l] = wsum - 2.f * part;
    }
  }
  // s-row (l = 196): from registers
  if (wv == 0) {
    float part = 0.f;
#pragma unroll
    for (int j = 0; j < 8; j++) {
      float P = sw8[j] * ag8[j];
      part = fmaf(wa8[j], __builtin_amdgcn_rcpf(1.f + P), part);
    }
    part = wred_sum(part);
    if (lane == 0) sh[196] = wsum - 2.f * part;
  }
  __syncthreads();
  float v = (tid < 197) ? sh[tid] : -1e30f;
  float mx = wred_max(v);
  if (lane == 0) red[wv] = mx;
  __syncthreads();
  mx = fmaxf(fmaxf(red[0], red[1]), fmaxf(red[2], red[3]));
  float p = (tid < 197) ? __expf(v - mx) : 0.f;
  float sm = wred_sum(p);
  if (lane == 0) red[4 + wv] = sm;
  __syncthreads();
  float inv = 1.f / (red[4] + red[5] + red[6] + red[7]);
  float a = p * inv;
  int dec = clen[b] - 1; if (dec < 1) dec = 1;
  float act = (t < dec) ? 1.f : 0.f;
  if (tid < 196) {
    alphas[(size_t)b * (T_ * L_) + (size_t)t * L_ + tid] = a * act;
    alphas_raw[(size_t)b * (T_ * L_) + (size_t)t * L_ + tid] = a;
  }
  if (tid == 196) {
    betas[b * T_ + t] = a * act;
    betas_raw[b * T_ + t] = a;
  }
}

// ---- tail: ctx(b,t,:) = alpha_raw(b,t,:) @ enc(b) + beta*s ; write projA ctx ----
__global__ __launch_bounds__(256) void ctx_tail(
    const float* __restrict__ alphas_raw, const float* __restrict__ betas_raw,
    const bf16* __restrict__ enc_r, const bf16* __restrict__ Aag,
    bf16* __restrict__ projA)
{
  int b = blockIdx.x, cs = blockIdx.y, tid = threadIdx.x;
  __shared__ float al[T_ * 200];
  for (int i = tid; i < T_ * 196; i += 256) {
    al[(i / 196) * 200 + (i % 196)] = alphas_raw[(size_t)b * (T_ * 196) + i];
  }
  __syncthreads();
  int ch = cs * 256 + tid;
  float acc[T_];
#pragma unroll
  for (int t = 0; t < T_; t++) acc[t] = 0.f;
  const short* ep = (const short*)(const void*)(enc_r) + (size_t)b * 196 * 512 + ch;
#pragma unroll 4
  for (int l = 0; l < 196; l++) {
    float e = b2f(ep[(size_t)l * 512]);
#pragma unroll
    for (int t = 0; t < T_; t++) acc[t] += al[t * 200 + l] * e;
  }
#pragma unroll
  for (int t = 0; t < T_; t++) {
    float beta = betas_raw[b * T_ + t];
    float sv = b2f(((const short*)(const void*)Aag)[(size_t)t * 131072 + pidx(b, 512 + ch, 1024)]);
    projA[(size_t)t * 131072 + pidx(b, 512 + ch, 1024)] = f2b(acc[t] + beta * sv);
  }
}

enum { EPI_F32 = 0, EPI_BF16 = 1, EPI_INIT = 2, EPI_PROJ = 3, EPI_OUT = 4, EPI_EXP2 = 5 };

// C = A (MxK packed) @ BT^T (BT: NxK packed), + bias.
template<int MFRAG, int NFRAG, int EPI>
__global__ __launch_bounds__(256) void gemm_pk(
    const bf16* __restrict__ A, const bf16* __restrict__ BT,
    const float* __restrict__ bias, void* __restrict__ Cp,
    const bf16* __restrict__ auxA, float* __restrict__ auxB,
    int M, int N, int K, int ldc, float oscale)
{
  const int lane = threadIdx.x & 63;
  const int wv = threadIdx.x >> 6;
  const int r16 = lane & 15;
  const int kg = lane >> 4;
  const int m0 = blockIdx.x * (MFRAG * 16);
  const int n0 = blockIdx.y * (NFRAG * 64) + wv * (NFRAG * 16);
  const int KT = K >> 5;

  f32x4 acc[MFRAG][NFRAG];
#pragma unroll
  for (int i = 0; i < MFRAG; i++)
#pragma unroll
    for (int j = 0; j < NFRAG; j++) acc[i][j] = f32x4{0.f, 0.f, 0.f, 0.f};

  const bf16* ap = A + (size_t)(m0 >> 4) * KT * 512 + lane * 8;
  const bf16* bp = BT + (size_t)(n0 >> 4) * KT * 512 + lane * 8;

#pragma unroll 4
  for (int kt = 0; kt < KT; kt++) {
    bf16x8 af[MFRAG], bfr[NFRAG];
#pragma unroll
    for (int i = 0; i < MFRAG; i++)
      af[i] = *(const bf16x8*)(const void*)(ap + ((size_t)i * KT + kt) * 512);
#pragma unroll
    for (int j = 0; j < NFRAG; j++)
      bfr[j] = *(const bf16x8*)(const void*)(bp + ((size_t)j * KT + kt) * 512);
#pragma unroll
    for (int i = 0; i < MFRAG; i++)
#pragma unroll
      for (int j = 0; j < NFRAG; j++)
        acc[i][j] = __builtin_amdgcn_mfma_f32_16x16x32_bf16(af[i], bfr[j], acc[i][j], 0, 0, 0);
  }

#pragma unroll
  for (int i = 0; i < MFRAG; i++)
#pragma unroll
    for (int j = 0; j < NFRAG; j++)
#pragma unroll
      for (int r = 0; r < 4; r++) {
        int m = m0 + i * 16 + kg * 4 + r;
        int n = n0 + j * 16 + r16;
        if (n >= N) continue;
        float v = acc[i][j][r] + bias[n];
        if constexpr (EPI == EPI_F32) {
          ((float*)Cp)[(size_t)m * ldc + n] = v * oscale;
        } else if constexpr (EPI == EPI_BF16) {
          ((bf16*)Cp)[(size_t)m * ldc + n] = f2b(v * oscale);
        } else if constexpr (EPI == EPI_EXP2) {
          ((bf16*)Cp)[(size_t)m * ldc + n] = f2b(__builtin_amdgcn_exp2f(ESCL * v));
        } else if constexpr (EPI == EPI_INIT) {
          float tv = tanhf(v);
          if (n < 512) ((bf16*)Cp)[pidx(m, n, 512)] = f2b(tv);   // h0 -> hbuf[0]
          else auxB[(size_t)m * 512 + (n - 512)] = tv;           // c0 (f32)
        } else if constexpr (EPI == EPI_PROJ) {
          v += b2f(((const short*)auxA)[pidx(m, n, 512)]);       // + x (xbuf)
          ((bf16*)Cp)[pidx(m, n, 512)] = f2b(v);
        } else {  // EPI_OUT: preds[b, t, n], row = t*128+b
          int t = m >> 7, b = m & 127;
          ((float*)Cp)[(size_t)b * (T_ * V_) + (size_t)t * V_ + n] = v;
        }
      }
}

// ---- fused multi-job packed-transpose ----
#define NJOBS 10
struct TJobs {
  const float* top[NJOBS];
  const float* bot[NJOBS];
  bf16* dst[NJOBS];
  int ncols[NJOBS];
  int ktop[NJOBS];
  int K[NJOBS];
  long cum[NJOBS + 1];
};

__global__ void trans_pack_multi(TJobs J, long total)
{
  for (long u = (long)blockIdx.x * blockDim.x + threadIdx.x; u < total;
       u += (long)gridDim.x * blockDim.x) {
    int j = 0;
#pragma unroll
    for (int q = 1; q < NJOBS; q++) j += (u >= J.cum[q]) ? 1 : 0;
    long t8 = u - J.cum[j];
    int K = J.K[j], KT = K >> 5, ktop = J.ktop[j], ncols = J.ncols[j];
    const float* top = J.top[j];
    const float* bot = J.bot[j];
    int r = (int)(t8 & 15);
    int kg = (int)((t8 >> 4) & 3);
    long tile = t8 >> 6;
    int kt = (int)(tile % KT);
    int rt = (int)(tile / KT);
    int n = rt * 16 + r;
    int kb = kt * 32 + kg * 8;
    bf16x8 out;
#pragma unroll
    for (int jj = 0; jj < 8; jj++) {
      int k = kb + jj;
      float v = 0.f;
      if (n < ncols) {
        if (k < ktop) { if (top) v = top[(size_t)k * ncols + n]; }
        else if (bot) { v = bot[(size_t)(k - ktop) * ncols + n]; }
      }
      out[jj] = f2bs(v);
    }
    *(bf16x8*)(void*)(J.dst[j] + t8 * 8) = out;
  }
}

// Packed-transpose (single job) — used post-scan for WT_lo.
__global__ void trans_pack(const float* __restrict__ top, const float* __restrict__ bot,
                           bf16* __restrict__ dst, int ncols, long nElem8, int ktop, int K)
{
  int KT = K >> 5;
  for (long t8 = (long)blockIdx.x * blockDim.x + threadIdx.x; t8 < nElem8;
       t8 += (long)gridDim.x * blockDim.x) {
    int r = (int)(t8 & 15);
    int kg = (int)((t8 >> 4) & 3);
    long tile = t8 >> 6;
    int kt = (int)(tile % KT);
    int rt = (int)(tile / KT);
    int n = rt * 16 + r;
    int kb = kt * 32 + kg * 8;
    bf16x8 out;
#pragma unroll
    for (int j = 0; j < 8; j++) {
      int k = kb + j;
      float v = 0.f;
      if (n < ncols) {
        if (k < ktop) { if (top) v = top[(size_t)k * ncols + n]; }
        else if (bot) { v = bot[(size_t)(k - ktop) * ncols + n]; }
      }
      out[j] = f2bs(v);
    }
    *(bf16x8*)(void*)(dst + t8 * 8) = out;
  }
}

// enc (f32 row-major) -> enc_p (bf16 packed) AND enc_r (bf16 row-major)
__global__ void conv_pack(const float* __restrict__ src, bf16* __restrict__ dst,
                          bf16* __restrict__ dst_row, long nElem8)
{
  for (long t8 = (long)blockIdx.x * blockDim.x + threadIdx.x; t8 < nElem8;
       t8 += (long)gridDim.x * blockDim.x) {
    int r = (int)(t8 & 15);
    int kg = (int)((t8 >> 4) & 3);
    long tile = t8 >> 6;
    int kt = (int)(tile & 15);           // KT = 16 (K=512)
    int rt = (int)(tile >> 4);
    size_t rowoff = ((size_t)(rt * 16 + r)) * 512 + kt * 32 + kg * 8;
    const float* s = src + rowoff;
    bf16x8 out;
#pragma unroll
    for (int j = 0; j < 8; j++) out[j] = f2bs(s[j]);
    *(bf16x8*)(void*)(dst + t8 * 8) = out;
    *(bf16x8*)(void*)(dst_row + rowoff) = out;
  }
}

__global__ void bias_comb(const float* __restrict__ b_lstm, const float* __restrict__ b_s,
                          const float* __restrict__ b_g, const float* __restrict__ b_sa,
                          const float* __restrict__ b_Lh, const float* __restrict__ b_Lz,
                          const float* __restrict__ b_ih, const float* __restrict__ b_ic,
                          float* __restrict__ bg, float* __restrict__ ba,
                          float* __restrict__ bp, float* __restrict__ bi)
{
  int i = blockIdx.x * blockDim.x + threadIdx.x;
  if (i < 2560) bg[i] = (i < 2048) ? b_lstm[i] : b_s[i - 2048];
  if (i < 1024) ba[i] = (i < 512) ? b_g[i] : b_sa[i - 512];
  if (i < 512)  bp[i] = b_Lh[i] + b_Lz[i];
  if (i < 1024) bi[i] = (i < 512) ? b_ih[i] : b_ic[i - 512];
}

__global__ __launch_bounds__(128) void mean_enc(const float* __restrict__ enc,
                                                bf16* __restrict__ mb)
{
  int b = blockIdx.x, c = blockIdx.y * 128 + threadIdx.x;
  float s = 0.f;
  for (int l = 0; l < L_; l++) s += enc[((size_t)b * L_ + l) * 512 + c];
  mb[pidx(b, c, 512)] = f2b(s * (1.f / (float)L_));
}

__global__ void gather_x(const float* __restrict__ emb, const int* __restrict__ caps,
                         bf16* __restrict__ xbuf)
{
  int tb = blockIdx.x;          // t*128 + b
  int t = tb >> 7, b = tb & 127;
  int word = caps[b * 26 + t];
  int c0 = threadIdx.x * 8;
  const float* src = emb + (size_t)word * 512 + c0;
  bf16* dst = xbuf + pidx(tb, c0, 512);
  bf16x8 out;
#pragma unroll
  for (int j = 0; j < 8; j++) out[j] = f2bs(src[j]);
  *(bf16x8*)(void*)dst = out;
}

extern "C" void kernel_launch(void* const* d_in, const int* in_sizes, int n_in,
                              void* d_out, int out_size, void* d_ws, size_t ws_size,
                              hipStream_t stream)
{
  const float* enc      = (const float*)d_in[0];
  const int*   caps     = (const int*)d_in[1];
  const int*   clen     = (const int*)d_in[2];
  const float* emb      = (const float*)d_in[3];
  const float* W_ih     = (const float*)d_in[4];
  const float* W_hh     = (const float*)d_in[5];
  const float* b_lstm   = (const float*)d_in[6];
  const float* Wx_s     = (const float*)d_in[7];
  const float* Wh_s     = (const float*)d_in[8];
  const float* b_s      = (const float*)d_in[9];
  const float* W_v      = (const float*)d_in[10];
  const float* b_v      = (const float*)d_in[11];
  const float* W_g      = (const float*)d_in[12];
  const float* b_g      = (const float*)d_in[13];
  const float* W_s_att  = (const float*)d_in[14];
  const float* b_sa     = (const float*)d_in[15];
  const float* w_a      = (const float*)d_in[16];
  const float* W_init_h = (const float*)d_in[17];
  const float* b_init_h = (const float*)d_in[18];
  const float* W_init_c = (const float*)d_in[19];
  const float* b_init_c = (const float*)d_in[20];
  const float* W_Lh     = (const float*)d_in[21];
  const float* b_Lh     = (const float*)d_in[22];
  const float* W_Lz     = (const float*)d_in[23];
  const float* b_Lz     = (const float*)d_in[24];
  const float* W_Lo     = (const float*)d_in[25];
  const float* b_Lo     = (const float*)d_in[26];

  float* preds  = (float*)d_out;
  float* alphas = preds + (size_t)B_ * T_ * V_;
  float* betas  = alphas + (size_t)B_ * T_ * L_;

  char* ws = (char*)d_ws;
  size_t off = 0;
  auto alloc = [&](size_t bytes) -> void* {
    void* p = ws + off;
    off = (off + bytes + 255) & ~(size_t)255;
    return p;
  };
  bf16*  enc_p  = (bf16*)alloc((size_t)B_ * L_ * 512 * 2);   // overlay region later
  bf16*  enc_r  = (bf16*)alloc((size_t)B_ * L_ * 512 * 2);
  bf16*  attv_b = (bf16*)alloc((size_t)B_ * L_ * 512 * 2);
  bf16*  WT_gx  = (bf16*)alloc((size_t)2560 * 512 * 2);
  bf16*  WT_gh  = (bf16*)alloc((size_t)2560 * 512 * 2);
  bf16*  WT_a   = (bf16*)alloc((size_t)1024 * 1024 * 2);
  bf16*  WT_p   = (bf16*)alloc((size_t)512 * 1024 * 2);
  bf16*  WT_v   = (bf16*)alloc((size_t)512 * 512 * 2);
  bf16*  WT_i   = (bf16*)alloc((size_t)1024 * 512 * 2);
  float* bgx    = (float*)alloc(2560 * 4);
  float* bax    = (float*)alloc(1024 * 4);
  float* bpx    = (float*)alloc(512 * 4);
  float* bix    = (float*)alloc(1024 * 4);
  bf16*  mean_b = (bf16*)alloc(128 * 512 * 2);
  bf16*  xbuf   = (bf16*)alloc((size_t)T_ * 128 * 512 * 2);
  bf16*  hbuf   = (bf16*)alloc((size_t)(T_ + 1) * 128 * 512 * 2);
  bf16*  projA  = (bf16*)alloc((size_t)T_ * 128 * 1024 * 2);
  bf16*  agsw_b = (bf16*)alloc((size_t)T_ * 128 * 1024 * 2);
  float* cbuf   = (float*)alloc(128 * 512 * 4);
  unsigned* bar = (unsigned*)alloc(8192);
  if (off > ws_size) return;  // loud validation failure if ws too small

  // Overlays in the dead enc_p region (25,690,112 B):
  //   xg (16,384,000) | Aag (6,553,600) | alphas_raw (2,508,800) | betas_raw (12,800)
  bf16*  xg         = (bf16*)enc_p;               // written AFTER att_v GEMM
  bf16*  Aag        = (bf16*)((char*)enc_p + 16384000);
  float* alphas_raw = (float*)((char*)enc_p + 22937600);
  float* betas_raw  = (float*)((char*)enc_p + 25446400);
  // Overlays in the dead xg region (post-scan):
  bf16*  WT_lo = xg;                              // 10,485,760 B (transposed post-scan)
  bf16*  projb = (bf16*)((char*)xg + 10485760);   // 3,276,800 B

  hipMemsetAsync(bar, 0, 8192, stream);

  // ---- prep ----
  bias_comb<<<dim3(10), dim3(256), 0, stream>>>(b_lstm, b_s, b_g, b_sa, b_Lh, b_Lz,
                                                b_init_h, b_init_c, bgx, bax, bpx, bix);
  // fused 10-job packed transpose
  {
    TJobs J;
    auto set = [&](int j, const float* top, const float* bot, bf16* dst,
                   int ncols, int nrows, int ktop, int K) {
      J.top[j] = top; J.bot[j] = bot; J.dst[j] = dst;
      J.ncols[j] = ncols; J.ktop[j] = ktop; J.K[j] = K;
      J.cum[j + 1] = J.cum[j] + (long)nrows * K / 8;
    };
    J.cum[0] = 0;
    set(0, W_ih, nullptr, WT_gx, 2048, 2048, 512, 512);
    set(1, Wx_s, nullptr, WT_gx + (size_t)2048 * 512, 512, 512, 512, 512);
    set(2, W_hh, nullptr, WT_gh, 2048, 2048, 512, 512);
    set(3, Wh_s, nullptr, WT_gh + (size_t)2048 * 512, 512, 512, 512, 512);
    set(4, W_Lh, W_Lz, WT_p, 512, 512, 512, 1024);
    set(5, W_g, nullptr, WT_a, 512, 512, 512, 1024);
    set(6, nullptr, W_s_att, WT_a + (size_t)512 * 1024, 512, 512, 512, 1024);
    set(7, W_v, nullptr, WT_v, 512, 512, 512, 512);
    set(8, W_init_h, nullptr, WT_i, 512, 512, 512, 512);
    set(9, W_init_c, nullptr, WT_i + (size_t)512 * 512, 512, 512, 512, 512);
    long total = J.cum[NJOBS];
    int blocks = (int)((total + 255) / 256);
    if (blocks > 2048) blocks = 2048;
    trans_pack_multi<<<dim3(blocks), dim3(256), 0, stream>>>(J, total);
  }
  conv_pack<<<dim3(4096), dim3(256), 0, stream>>>(enc, enc_p, enc_r,
                                                  (long)B_ * L_ * 512 / 8);
  mean_enc<<<dim3(128, 4), dim3(128), 0, stream>>>(enc, mean_b);
  gather_x<<<dim3(T_ * 128), dim3(64), 0, stream>>>(emb, caps, xbuf);

  // h0 -> hbuf[0] (packed K=512), c0 -> cbuf (f32)
  gemm_pk<1, 1, EPI_INIT><<<dim3(8, 16), dim3(256), 0, stream>>>(
      mean_b, WT_i, bix, (void*)hbuf, nullptr, cbuf, 128, 1024, 512, 0, 1.f);
  // Ea = exp2(ESCL*(enc @ W_v + b_v))  (bf16 row-major) — LAST consumer of enc_p
  gemm_pk<4, 2, EPI_EXP2><<<dim3(392, 4), dim3(256), 0, stream>>>(
      enc_p, WT_v, b_v, attv_b, nullptr, nullptr, B_ * L_, 512, 512, 512, 1.f);
  // xg = X_all @ [W_ih;Wx_s] + bias  (3200 x 2560 x 512, bf16, overlays enc_p)
  gemm_pk<4, 2, EPI_BF16><<<dim3(50, 20), dim3(256), 0, stream>>>(
      xbuf, WT_gx, bgx, xg, nullptr, nullptr, T_ * 128, 2560, 512, 2560, 1.f);

  // ---- persistent 25-step weight-stationary scan (8 groups x 32 blocks) ----
  scan_ws<<<dim3(256), dim3(256), 0, stream>>>(hbuf, WT_gh, xg, cbuf, Aag, projA, bar);

  // ---- batched attention pipeline ----
  // Eb = exp2(ESCL*([h|s]_all @ blockdiag(W_g, W_s_att) + [b_g|b_sa]))  (bf16)
  gemm_pk<4, 2, EPI_EXP2><<<dim3(50, 8), dim3(256), 0, stream>>>(
      Aag, WT_a, bax, agsw_b, nullptr, nullptr, T_ * 128, 1024, 1024, 1024, 1.f);
  // e-scores + softmax for all (b,t)
  e_batch<<<dim3(128, 25), dim3(256), 0, stream>>>(
      attv_b, agsw_b, w_a, clen, alphas, betas, alphas_raw, betas_raw);
  // WT_lo transpose (overlays dead xg) — must run after the scan
  {
    long n8 = (long)10240 * 512 / 8;
    trans_pack<<<dim3(2048), dim3(256), 0, stream>>>(W_Lo, nullptr, WT_lo,
                                                     10000, n8, 512, 512);
  }
  // ctx -> projA ctx-slots (reads enc ONCE, batched over all t)
  ctx_tail<<<dim3(128, 2), dim3(256), 0, stream>>>(alphas_raw, betas_raw, enc_r,
                                                   Aag, projA);
  // proj = x + [h|ctx] @ [W_Lh;W_Lz] + b   (3200 x 512 x 1024, packed out)
  gemm_pk<4, 2, EPI_PROJ><<<dim3(50, 4), dim3(256), 0, stream>>>(
      projA, WT_p, bpx, projb, xbuf, nullptr, T_ * 128, 512, 1024, 0, 1.f);
  // preds = proj @ W_Lo + b_Lo  (3200 x 10000 x 512)
  gemm_pk<4, 4, EPI_OUT><<<dim3(50, 40), dim3(256), 0, stream>>>(
      projb, WT_lo, b_Lo, preds, nullptr, nullptr, T_ * 128, V_, 512, 0, 1.f);
}

// Round 15
// 388.914 us; speedup vs baseline: 1.2017x; 1.0099x over previous
//
#include <hip/hip_runtime.h>
#include <hip/hip_bf16.h>
#include <cstdint>
#include <cstddef>

using bf16 = __hip_bfloat16;
typedef __attribute__((ext_vector_type(4))) float f32x4;
typedef __attribute__((ext_vector_type(8))) short bf16x8;

#define B_ 128
#define L_ 196
#define T_ 25
#define V_ 10000
#define ESCL 2.885390081777927f   // 2*log2(e): tanh(z) = 1 - 2/(1+exp2(z*ESCL))

__device__ __forceinline__ float b2f(short s) {
  unsigned u = ((unsigned)(unsigned short)s) << 16;
  return __uint_as_float(u);
}
__device__ __forceinline__ bf16 f2b(float f) { return __float2bfloat16(f); }
__device__ __forceinline__ short f2bs(float f) {
  return __builtin_bit_cast(short, __float2bfloat16(f));
}
__device__ __forceinline__ float sigf(float x) { return 1.f / (1.f + __expf(-x)); }
__device__ __forceinline__ float tanh_fast(float x) { return 1.f - 2.f / (1.f + __expf(2.f * x)); }

// sc1 write-through stores (push to L3); relaxed agent-scope loads for spin.
__device__ __forceinline__ void cst_u32(unsigned* p, unsigned v) {
  __hip_atomic_store(p, v, __ATOMIC_RELAXED, __HIP_MEMORY_SCOPE_AGENT);
}
__device__ __forceinline__ unsigned cld_u32(const unsigned* p) {
  return __hip_atomic_load((unsigned*)p, __ATOMIC_RELAXED, __HIP_MEMORY_SCOPE_AGENT);
}

// Fragment-packed layout: 16x32 tiles, tile-row-major; element (r,c) at
// (((r>>4)*KT + (c>>5))*64 + ((c&31)>>3)*16 + (r&15))*8 + (c&7).
__device__ __forceinline__ size_t pidx(int row, int col, int K) {
  int KT = K >> 5;
  return (((size_t)(row >> 4) * KT + (col >> 5)) * 64 +
          (size_t)(((col & 31) >> 3) * 16 + (row & 15))) * 8 + (col & 7);
}

__device__ __forceinline__ float wred_sum(float x) {
#pragma unroll
  for (int off = 32; off >= 1; off >>= 1) x += __shfl_xor(x, off, 64);
  return x;
}
__device__ __forceinline__ float wred_max(float x) {
#pragma unroll
  for (int off = 32; off >= 1; off >>= 1) x = fmaxf(x, __shfl_xor(x, off, 64));
  return x;
}

// ---- monotone single-counter group barrier (32 blocks per group) ----
__device__ __forceinline__ void gbar_m(unsigned* bs, int mi, unsigned tgt) {
  asm volatile("s_waitcnt vmcnt(0)" ::: "memory");
  __syncthreads();
  if (threadIdx.x == 0) {
    unsigned* c = bs + mi * 64;       // 256B apart per group
    unsigned a = __hip_atomic_fetch_add(c, 1u, __ATOMIC_RELAXED,
                                        __HIP_MEMORY_SCOPE_AGENT);
    if (a + 1u < tgt) {
      while (cld_u32(c) < tgt) __builtin_amdgcn_s_sleep(1);
    }
  }
  __syncthreads();
}

// ---- persistent scan: weight-stationary, 256 blocks = 8 mi-groups x 32 di ----
// xg values for step t+1 are prefetched BEFORE the barrier (t-only dependent),
// so the post-barrier critical path starts at the h loads.
__global__ __launch_bounds__(256) void scan_ws(
    bf16* __restrict__ hbuf,        // (T_+1) x (128x512 packed) h state
    const bf16* __restrict__ WT_gh, // 2560x512 packed (h-half weights)
    const bf16* __restrict__ xg,    // T_ x 128 x 2560 bf16 row-major: x@W + bias
    float* __restrict__ cbuf,       // 128x512 f32 cell state
    bf16* __restrict__ Aag,         // T_ x 128x1024 packed [h|s]  (post-scan)
    bf16* __restrict__ projA,       // T_ x 128x1024 packed [h|ctx] (post-scan)
    unsigned* __restrict__ bar)
{
  const int tid = threadIdx.x;
  const int wv = tid >> 6, lane = tid & 63;
  const int mi = blockIdx.x & 7;        // group: same XCD slot under round-robin
  const int di = blockIdx.x >> 3;       // 0..31 (cols di*16..+15)
  __shared__ f32x4 pacc[4][5][64];      // 20 KB split-K partials

  // ---- weight-stationary B fragments: bw[g][kk], kt = wv*4+kk ----
  bf16x8 bw[5][4];
#pragma unroll
  for (int g = 0; g < 5; g++)
#pragma unroll
    for (int kk = 0; kk < 4; kk++)
      bw[g][kk] = *(const bf16x8*)(const void*)(
          WT_gh + (size_t)(g * 32 + di) * 8192 + (size_t)(wv * 4 + kk) * 512 + lane * 8);

  const int el_r16 = lane & 15, el_r = lane >> 4;
  const int m_pw = mi * 16 + wv * 4 + el_r;
  const int d_pw = di * 16 + el_r16;
  const size_t qlo = pidx(m_pw, d_pw, 512);
  const size_t plo = pidx(m_pw, d_pw, 1024);
  const size_t phi = pidx(m_pw, 512 + d_pw, 1024);
  float* cp = cbuf + m_pw * 512 + d_pw;
  const size_t xoff = (size_t)m_pw * 2560 + d_pw;

  // preload xg for step 0
  const short* xr = (const short*)(const void*)(xg + xoff);
  float xv0 = b2f(xr[0]);
  float xv1 = b2f(xr[512]);
  float xv2 = b2f(xr[1024]);
  float xv3 = b2f(xr[1536]);
  float xv4 = b2f(xr[2048]);

  for (int tt = 0; tt < T_; ++tt) {
    const bf16* ap = hbuf + (size_t)tt * 65536 + (size_t)mi * 8192 + lane * 8;
    bf16x8 a0 = *(const bf16x8*)(const void*)(ap + (size_t)(wv * 4 + 0) * 512);
    bf16x8 a1 = *(const bf16x8*)(const void*)(ap + (size_t)(wv * 4 + 1) * 512);
    bf16x8 a2 = *(const bf16x8*)(const void*)(ap + (size_t)(wv * 4 + 2) * 512);
    bf16x8 a3 = *(const bf16x8*)(const void*)(ap + (size_t)(wv * 4 + 3) * 512);
    f32x4 acc[5];
#pragma unroll
    for (int g = 0; g < 5; g++) acc[g] = f32x4{0.f, 0.f, 0.f, 0.f};
#pragma unroll
    for (int g = 0; g < 5; g++) {
      acc[g] = __builtin_amdgcn_mfma_f32_16x16x32_bf16(a0, bw[g][0], acc[g], 0, 0, 0);
      acc[g] = __builtin_amdgcn_mfma_f32_16x16x32_bf16(a1, bw[g][1], acc[g], 0, 0, 0);
      acc[g] = __builtin_amdgcn_mfma_f32_16x16x32_bf16(a2, bw[g][2], acc[g], 0, 0, 0);
      acc[g] = __builtin_amdgcn_mfma_f32_16x16x32_bf16(a3, bw[g][3], acc[g], 0, 0, 0);
    }
#pragma unroll
    for (int g = 0; g < 5; g++) pacc[wv][g][lane] = acc[g];
    __syncthreads();
    float G0 = 0.f, G1 = 0.f, G2 = 0.f, G3 = 0.f, G4 = 0.f;
#pragma unroll
    for (int q = 0; q < 4; q++) {
      int sl = wv * 16 + el_r16;
      G0 += pacc[q][0][sl][el_r];
      G1 += pacc[q][1][sl][el_r];
      G2 += pacc[q][2][sl][el_r];
      G3 += pacc[q][3][sl][el_r];
      G4 += pacc[q][4][sl][el_r];
    }
    float cn = sigf(G1 + xv1) * (*cp) + sigf(G0 + xv0) * tanh_fast(G2 + xv2);
    float tcn = tanh_fast(cn);
    float hn = sigf(G3 + xv3) * tcn;
    float ss = sigf(G4 + xv4) * tcn;
    float hn1 = __shfl_down(hn, 1);
    float ss1 = __shfl_down(ss, 1);
    unsigned hp = 0, sp = 0;
    bool wr = !(el_r16 & 1);
    if (wr) {
      hp = (unsigned)(unsigned short)f2bs(hn) |
           ((unsigned)(unsigned short)f2bs(hn1) << 16);
      sp = (unsigned)(unsigned short)f2bs(ss) |
           ((unsigned)(unsigned short)f2bs(ss1) << 16);
      cst_u32((unsigned*)(void*)(hbuf + (size_t)(tt + 1) * 65536 + qlo), hp);
    }
    // prefetch xg for next step (independent of h); completes during barrier
    int tn = (tt + 1 < T_) ? tt + 1 : tt;
    const short* xrn = (const short*)(const void*)(xg + (size_t)tn * (128 * 2560) + xoff);
    float nx0 = b2f(xrn[0]);
    float nx1 = b2f(xrn[512]);
    float nx2 = b2f(xrn[1024]);
    float nx3 = b2f(xrn[1536]);
    float nx4 = b2f(xrn[2048]);
    if (tt < T_ - 1) gbar_m(bar, mi, 32u * (unsigned)(tt + 1));
    *cp = cn;
    if (wr) {
      bf16* pA = projA + (size_t)tt * 131072;
      bf16* AagT = Aag + (size_t)tt * 131072;
      *(unsigned*)(void*)(pA + plo) = hp;
      *(unsigned*)(void*)(AagT + plo) = hp;
      *(unsigned*)(void*)(AagT + phi) = sp;
    }
    xv0 = nx0; xv1 = nx1; xv2 = nx2; xv3 = nx3; xv4 = nx4;
  }
}

// ---- batched e-scores + softmax; grid (128, 25) ----
// attv/agsw store E = exp2(ESCL * preact):
//   e = Wsum - 2 * sum_d wa_d * rcp(fma(Ea, Eb, 1))
__global__ __launch_bounds__(256) void e_batch(
    const bf16* __restrict__ attv, const bf16* __restrict__ agsw_all,
    const float* __restrict__ w_a, const int* __restrict__ clen,
    float* __restrict__ alphas, float* __restrict__ betas,
    float* __restrict__ alphas_raw, float* __restrict__ betas_raw)
{
  __shared__ float sh[200];
  __shared__ float red[8];
  int b = blockIdx.x, t = blockIdx.y;
  int tid = threadIdx.x, wv = tid >> 6, lane = tid & 63;
  const bf16* ag = agsw_all + ((size_t)t * 128 + b) * 1024;
  int a0 = lane * 8;
  float ag8[8], wa8[8], sw8[8];
  float wsum = 0.f;
  bf16x8 agv = *(const bf16x8*)(const void*)(ag + a0);
  bf16x8 swv = *(const bf16x8*)(const void*)(ag + 512 + a0);
#pragma unroll
  for (int j = 0; j < 8; j++) {
    ag8[j] = b2f(agv[j]);         // Eb
    wa8[j] = w_a[a0 + j];
    sw8[j] = b2f(swv[j]);         // Es
    wsum += wa8[j];
  }
  wsum = wred_sum(wsum);
  // main rows l < 196
  for (int base = wv; base < 196; base += 16) {
    bf16x8 av[4];
#pragma unroll
    for (int q = 0; q < 4; q++) {
      int l = base + 4 * q;
      if (l < 196)
        av[q] = *(const bf16x8*)(const void*)(attv + ((size_t)(b * 196 + l)) * 512 + a0);
    }
#pragma unroll
    for (int q = 0; q < 4; q++) {
      int l = base + 4 * q;
      if (l >= 196) continue;    // wave-uniform (only final iteration)
      float part = 0.f;
#pragma unroll
      for (int j = 0; j < 8; j++) {
        float den = fmaf(b2f(av[q][j]), ag8[j], 1.f);
        part = fmaf(wa8[j], __builtin_amdgcn_rcpf(den), part);
      }
      part = wred_sum(part);
      if (lane == 0) sh[l] = wsum - 2.f * part;
    }
  }
  // s-row (l = 196): from registers
  if (wv == 0) {
    float part = 0.f;
#pragma unroll
    for (int j = 0; j < 8; j++) {
      float den = fmaf(sw8[j], ag8[j], 1.f);
      part = fmaf(wa8[j], __builtin_amdgcn_rcpf(den), part);
    }
    part = wred_sum(part);
    if (lane == 0) sh[196] = wsum - 2.f * part;
  }
  __syncthreads();
  float v = (tid < 197) ? sh[tid] : -1e30f;
  float mx = wred_max(v);
  if (lane == 0) red[wv] = mx;
  __syncthreads();
  mx = fmaxf(fmaxf(red[0], red[1]), fmaxf(red[2], red[3]));
  float p = (tid < 197) ? __expf(v - mx) : 0.f;
  float sm = wred_sum(p);
  if (lane == 0) red[4 + wv] = sm;
  __syncthreads();
  float inv = 1.f / (red[4] + red[5] + red[6] + red[7]);
  float a = p * inv;
  int dec = clen[b] - 1; if (dec < 1) dec = 1;
  float act = (t < dec) ? 1.f : 0.f;
  if (tid < 196) {
    alphas[(size_t)b * (T_ * L_) + (size_t)t * L_ + tid] = a * act;
    alphas_raw[(size_t)b * (T_ * L_) + (size_t)t * L_ + tid] = a;
  }
  if (tid == 196) {
    betas[b * T_ + t] = a * act;
    betas_raw[b * T_ + t] = a;
  }
}

// ---- tail: ctx(b,t,:) = alpha_raw(b,t,:) @ enc(b) + beta*s ; write projA ctx ----
__global__ __launch_bounds__(256) void ctx_tail(
    const float* __restrict__ alphas_raw, const float* __restrict__ betas_raw,
    const bf16* __restrict__ enc_r, const bf16* __restrict__ Aag,
    bf16* __restrict__ projA)
{
  int b = blockIdx.x, cs = blockIdx.y, tid = threadIdx.x;
  __shared__ float al[T_ * 200];
  for (int i = tid; i < T_ * 196; i += 256) {
    al[(i / 196) * 200 + (i % 196)] = alphas_raw[(size_t)b * (T_ * 196) + i];
  }
  __syncthreads();
  int ch = cs * 256 + tid;
  float acc[T_];
#pragma unroll
  for (int t = 0; t < T_; t++) acc[t] = 0.f;
  const short* ep = (const short*)(const void*)(enc_r) + (size_t)b * 196 * 512 + ch;
#pragma unroll 4
  for (int l = 0; l < 196; l++) {
    float e = b2f(ep[(size_t)l * 512]);
#pragma unroll
    for (int t = 0; t < T_; t++) acc[t] += al[t * 200 + l] * e;
  }
#pragma unroll
  for (int t = 0; t < T_; t++) {
    float beta = betas_raw[b * T_ + t];
    float sv = b2f(((const short*)(const void*)Aag)[(size_t)t * 131072 + pidx(b, 512 + ch, 1024)]);
    projA[(size_t)t * 131072 + pidx(b, 512 + ch, 1024)] = f2b(acc[t] + beta * sv);
  }
}

enum { EPI_F32 = 0, EPI_BF16 = 1, EPI_INIT = 2, EPI_PROJ = 3, EPI_OUT = 4, EPI_EXP2 = 5 };

// C = A (MxK packed) @ BT^T (BT: NxK packed), + bias.
template<int MFRAG, int NFRAG, int EPI>
__global__ __launch_bounds__(256) void gemm_pk(
    const bf16* __restrict__ A, const bf16* __restrict__ BT,
    const float* __restrict__ bias, void* __restrict__ Cp,
    const bf16* __restrict__ auxA, float* __restrict__ auxB,
    int M, int N, int K, int ldc, float oscale)
{
  const int lane = threadIdx.x & 63;
  const int wv = threadIdx.x >> 6;
  const int r16 = lane & 15;
  const int kg = lane >> 4;
  const int m0 = blockIdx.x * (MFRAG * 16);
  const int n0 = blockIdx.y * (NFRAG * 64) + wv * (NFRAG * 16);
  const int KT = K >> 5;

  f32x4 acc[MFRAG][NFRAG];
#pragma unroll
  for (int i = 0; i < MFRAG; i++)
#pragma unroll
    for (int j = 0; j < NFRAG; j++) acc[i][j] = f32x4{0.f, 0.f, 0.f, 0.f};

  const bf16* ap = A + (size_t)(m0 >> 4) * KT * 512 + lane * 8;
  const bf16* bp = BT + (size_t)(n0 >> 4) * KT * 512 + lane * 8;

#pragma unroll 4
  for (int kt = 0; kt < KT; kt++) {
    bf16x8 af[MFRAG], bfr[NFRAG];
#pragma unroll
    for (int i = 0; i < MFRAG; i++)
      af[i] = *(const bf16x8*)(const void*)(ap + ((size_t)i * KT + kt) * 512);
#pragma unroll
    for (int j = 0; j < NFRAG; j++)
      bfr[j] = *(const bf16x8*)(const void*)(bp + ((size_t)j * KT + kt) * 512);
#pragma unroll
    for (int i = 0; i < MFRAG; i++)
#pragma unroll
      for (int j = 0; j < NFRAG; j++)
        acc[i][j] = __builtin_amdgcn_mfma_f32_16x16x32_bf16(af[i], bfr[j], acc[i][j], 0, 0, 0);
  }

#pragma unroll
  for (int i = 0; i < MFRAG; i++)
#pragma unroll
    for (int j = 0; j < NFRAG; j++)
#pragma unroll
      for (int r = 0; r < 4; r++) {
        int m = m0 + i * 16 + kg * 4 + r;
        int n = n0 + j * 16 + r16;
        if (n >= N) continue;
        float v = acc[i][j][r] + bias[n];
        if constexpr (EPI == EPI_F32) {
          ((float*)Cp)[(size_t)m * ldc + n] = v * oscale;
        } else if constexpr (EPI == EPI_BF16) {
          ((bf16*)Cp)[(size_t)m * ldc + n] = f2b(v * oscale);
        } else if constexpr (EPI == EPI_EXP2) {
          ((bf16*)Cp)[(size_t)m * ldc + n] = f2b(__builtin_amdgcn_exp2f(ESCL * v));
        } else if constexpr (EPI == EPI_INIT) {
          float tv = tanhf(v);
          if (n < 512) ((bf16*)Cp)[pidx(m, n, 512)] = f2b(tv);   // h0 -> hbuf[0]
          else auxB[(size_t)m * 512 + (n - 512)] = tv;           // c0 (f32)
        } else if constexpr (EPI == EPI_PROJ) {
          v += b2f(((const short*)auxA)[pidx(m, n, 512)]);       // + x (xbuf)
          ((bf16*)Cp)[pidx(m, n, 512)] = f2b(v);
        } else {  // EPI_OUT: preds[b, t, n], row = t*128+b
          int t = m >> 7, b = m & 127;
          ((float*)Cp)[(size_t)b * (T_ * V_) + (size_t)t * V_ + n] = v;
        }
      }
}

// ---- fused multi-job packed-transpose ----
#define NJOBS 10
struct TJobs {
  const float* top[NJOBS];
  const float* bot[NJOBS];
  bf16* dst[NJOBS];
  int ncols[NJOBS];
  int ktop[NJOBS];
  int K[NJOBS];
  long cum[NJOBS + 1];
};

__global__ void trans_pack_multi(TJobs J, long total)
{
  for (long u = (long)blockIdx.x * blockDim.x + threadIdx.x; u < total;
       u += (long)gridDim.x * blockDim.x) {
    int j = 0;
#pragma unroll
    for (int q = 1; q < NJOBS; q++) j += (u >= J.cum[q]) ? 1 : 0;
    long t8 = u - J.cum[j];
    int K = J.K[j], KT = K >> 5, ktop = J.ktop[j], ncols = J.ncols[j];
    const float* top = J.top[j];
    const float* bot = J.bot[j];
    int r = (int)(t8 & 15);
    int kg = (int)((t8 >> 4) & 3);
    long tile = t8 >> 6;
    int kt = (int)(tile % KT);
    int rt = (int)(tile / KT);
    int n = rt * 16 + r;
    int kb = kt * 32 + kg * 8;
    bf16x8 out;
#pragma unroll
    for (int jj = 0; jj < 8; jj++) {
      int k = kb + jj;
      float v = 0.f;
      if (n < ncols) {
        if (k < ktop) { if (top) v = top[(size_t)k * ncols + n]; }
        else if (bot) { v = bot[(size_t)(k - ktop) * ncols + n]; }
      }
      out[jj] = f2bs(v);
    }
    *(bf16x8*)(void*)(J.dst[j] + t8 * 8) = out;
  }
}

// Packed-transpose (single job) — used post-scan for WT_lo.
__global__ void trans_pack(const float* __restrict__ top, const float* __restrict__ bot,
                           bf16* __restrict__ dst, int ncols, long nElem8, int ktop, int K)
{
  int KT = K >> 5;
  for (long t8 = (long)blockIdx.x * blockDim.x + threadIdx.x; t8 < nElem8;
       t8 += (long)gridDim.x * blockDim.x) {
    int r = (int)(t8 & 15);
    int kg = (int)((t8 >> 4) & 3);
    long tile = t8 >> 6;
    int kt = (int)(tile % KT);
    int rt = (int)(tile / KT);
    int n = rt * 16 + r;
    int kb = kt * 32 + kg * 8;
    bf16x8 out;
#pragma unroll
    for (int j = 0; j < 8; j++) {
      int k = kb + j;
      float v = 0.f;
      if (n < ncols) {
        if (k < ktop) { if (top) v = top[(size_t)k * ncols + n]; }
        else if (bot) { v = bot[(size_t)(k - ktop) * ncols + n]; }
      }
      out[j] = f2bs(v);
    }
    *(bf16x8*)(void*)(dst + t8 * 8) = out;
  }
}

// enc (f32 row-major) -> enc_p (bf16 packed) AND enc_r (bf16 row-major)
__global__ void conv_pack(const float* __restrict__ src, bf16* __restrict__ dst,
                          bf16* __restrict__ dst_row, long nElem8)
{
  for (long t8 = (long)blockIdx.x * blockDim.x + threadIdx.x; t8 < nElem8;
       t8 += (long)gridDim.x * blockDim.x) {
    int r = (int)(t8 & 15);
    int kg = (int)((t8 >> 4) & 3);
    long tile = t8 >> 6;
    int kt = (int)(tile & 15);           // KT = 16 (K=512)
    int rt = (int)(tile >> 4);
    size_t rowoff = ((size_t)(rt * 16 + r)) * 512 + kt * 32 + kg * 8;
    const float* s = src + rowoff;
    bf16x8 out;
#pragma unroll
    for (int j = 0; j < 8; j++) out[j] = f2bs(s[j]);
    *(bf16x8*)(void*)(dst + t8 * 8) = out;
    *(bf16x8*)(void*)(dst_row + rowoff) = out;
  }
}

__global__ void bias_comb(const float* __restrict__ b_lstm, const float* __restrict__ b_s,
                          const float* __restrict__ b_g, const float* __restrict__ b_sa,
                          const float* __restrict__ b_Lh, const float* __restrict__ b_Lz,
                          const float* __restrict__ b_ih, const float* __restrict__ b_ic,
                          float* __restrict__ bg, float* __restrict__ ba,
                          float* __restrict__ bp, float* __restrict__ bi)
{
  int i = blockIdx.x * blockDim.x + threadIdx.x;
  if (i < 2560) bg[i] = (i < 2048) ? b_lstm[i] : b_s[i - 2048];
  if (i < 1024) ba[i] = (i < 512) ? b_g[i] : b_sa[i - 512];
  if (i < 512)  bp[i] = b_Lh[i] + b_Lz[i];
  if (i < 1024) bi[i] = (i < 512) ? b_ih[i] : b_ic[i - 512];
}

__global__ __launch_bounds__(128) void mean_enc(const float* __restrict__ enc,
                                                bf16* __restrict__ mb)
{
  int b = blockIdx.x, c = blockIdx.y * 128 + threadIdx.x;
  float s = 0.f;
  for (int l = 0; l < L_; l++) s += enc[((size_t)b * L_ + l) * 512 + c];
  mb[pidx(b, c, 512)] = f2b(s * (1.f / (float)L_));
}

__global__ void gather_x(const float* __restrict__ emb, const int* __restrict__ caps,
                         bf16* __restrict__ xbuf)
{
  int tb = blockIdx.x;          // t*128 + b
  int t = tb >> 7, b = tb & 127;
  int word = caps[b * 26 + t];
  int c0 = threadIdx.x * 8;
  const float* src = emb + (size_t)word * 512 + c0;
  bf16* dst = xbuf + pidx(tb, c0, 512);
  bf16x8 out;
#pragma unroll
  for (int j = 0; j < 8; j++) out[j] = f2bs(src[j]);
  *(bf16x8*)(void*)dst = out;
}

extern "C" void kernel_launch(void* const* d_in, const int* in_sizes, int n_in,
                              void* d_out, int out_size, void* d_ws, size_t ws_size,
                              hipStream_t stream)
{
  const float* enc      = (const float*)d_in[0];
  const int*   caps     = (const int*)d_in[1];
  const int*   clen     = (const int*)d_in[2];
  const float* emb      = (const float*)d_in[3];
  const float* W_ih     = (const float*)d_in[4];
  const float* W_hh     = (const float*)d_in[5];
  const float* b_lstm   = (const float*)d_in[6];
  const float* Wx_s     = (const float*)d_in[7];
  const float* Wh_s     = (const float*)d_in[8];
  const float* b_s      = (const float*)d_in[9];
  const float* W_v      = (const float*)d_in[10];
  const float* b_v      = (const float*)d_in[11];
  const float* W_g      = (const float*)d_in[12];
  const float* b_g      = (const float*)d_in[13];
  const float* W_s_att  = (const float*)d_in[14];
  const float* b_sa     = (const float*)d_in[15];
  const float* w_a      = (const float*)d_in[16];
  const float* W_init_h = (const float*)d_in[17];
  const float* b_init_h = (const float*)d_in[18];
  const float* W_init_c = (const float*)d_in[19];
  const float* b_init_c = (const float*)d_in[20];
  const float* W_Lh     = (const float*)d_in[21];
  const float* b_Lh     = (const float*)d_in[22];
  const float* W_Lz     = (const float*)d_in[23];
  const float* b_Lz     = (const float*)d_in[24];
  const float* W_Lo     = (const float*)d_in[25];
  const float* b_Lo     = (const float*)d_in[26];

  float* preds  = (float*)d_out;
  float* alphas = preds + (size_t)B_ * T_ * V_;
  float* betas  = alphas + (size_t)B_ * T_ * L_;

  char* ws = (char*)d_ws;
  size_t off = 0;
  auto alloc = [&](size_t bytes) -> void* {
    void* p = ws + off;
    off = (off + bytes + 255) & ~(size_t)255;
    return p;
  };
  bf16*  enc_p  = (bf16*)alloc((size_t)B_ * L_ * 512 * 2);   // overlay region later
  bf16*  enc_r  = (bf16*)alloc((size_t)B_ * L_ * 512 * 2);
  bf16*  attv_b = (bf16*)alloc((size_t)B_ * L_ * 512 * 2);
  bf16*  WT_gx  = (bf16*)alloc((size_t)2560 * 512 * 2);
  bf16*  WT_gh  = (bf16*)alloc((size_t)2560 * 512 * 2);
  bf16*  WT_a   = (bf16*)alloc((size_t)1024 * 1024 * 2);
  bf16*  WT_p   = (bf16*)alloc((size_t)512 * 1024 * 2);
  bf16*  WT_v   = (bf16*)alloc((size_t)512 * 512 * 2);
  bf16*  WT_i   = (bf16*)alloc((size_t)1024 * 512 * 2);
  float* bgx    = (float*)alloc(2560 * 4);
  float* bax    = (float*)alloc(1024 * 4);
  float* bpx    = (float*)alloc(512 * 4);
  float* bix    = (float*)alloc(1024 * 4);
  bf16*  mean_b = (bf16*)alloc(128 * 512 * 2);
  bf16*  xbuf   = (bf16*)alloc((size_t)T_ * 128 * 512 * 2);
  bf16*  hbuf   = (bf16*)alloc((size_t)(T_ + 1) * 128 * 512 * 2);
  bf16*  projA  = (bf16*)alloc((size_t)T_ * 128 * 1024 * 2);
  bf16*  agsw_b = (bf16*)alloc((size_t)T_ * 128 * 1024 * 2);
  float* cbuf   = (float*)alloc(128 * 512 * 4);
  unsigned* bar = (unsigned*)alloc(8192);
  if (off > ws_size) return;  // loud validation failure if ws too small

  // Overlays in the dead enc_p region (25,690,112 B):
  //   xg (16,384,000) | Aag (6,553,600) | alphas_raw (2,508,800) | betas_raw (12,800)
  bf16*  xg         = (bf16*)enc_p;               // written AFTER att_v GEMM
  bf16*  Aag        = (bf16*)((char*)enc_p + 16384000);
  float* alphas_raw = (float*)((char*)enc_p + 22937600);
  float* betas_raw  = (float*)((char*)enc_p + 25446400);
  // Overlays in the dead xg region (post-scan):
  bf16*  WT_lo = xg;                              // 10,485,760 B (transposed post-scan)
  bf16*  projb = (bf16*)((char*)xg + 10485760);   // 3,276,800 B

  hipMemsetAsync(bar, 0, 8192, stream);

  // ---- prep ----
  bias_comb<<<dim3(10), dim3(256), 0, stream>>>(b_lstm, b_s, b_g, b_sa, b_Lh, b_Lz,
                                                b_init_h, b_init_c, bgx, bax, bpx, bix);
  // fused 10-job packed transpose
  {
    TJobs J;
    auto set = [&](int j, const float* top, const float* bot, bf16* dst,
                   int ncols, int nrows, int ktop, int K) {
      J.top[j] = top; J.bot[j] = bot; J.dst[j] = dst;
      J.ncols[j] = ncols; J.ktop[j] = ktop; J.K[j] = K;
      J.cum[j + 1] = J.cum[j] + (long)nrows * K / 8;
    };
    J.cum[0] = 0;
    set(0, W_ih, nullptr, WT_gx, 2048, 2048, 512, 512);
    set(1, Wx_s, nullptr, WT_gx + (size_t)2048 * 512, 512, 512, 512, 512);
    set(2, W_hh, nullptr, WT_gh, 2048, 2048, 512, 512);
    set(3, Wh_s, nullptr, WT_gh + (size_t)2048 * 512, 512, 512, 512, 512);
    set(4, W_Lh, W_Lz, WT_p, 512, 512, 512, 1024);
    set(5, W_g, nullptr, WT_a, 512, 512, 512, 1024);
    set(6, nullptr, W_s_att, WT_a + (size_t)512 * 1024, 512, 512, 512, 1024);
    set(7, W_v, nullptr, WT_v, 512, 512, 512, 512);
    set(8, W_init_h, nullptr, WT_i, 512, 512, 512, 512);
    set(9, W_init_c, nullptr, WT_i + (size_t)512 * 512, 512, 512, 512, 512);
    long total = J.cum[NJOBS];
    int blocks = (int)((total + 255) / 256);
    if (blocks > 2048) blocks = 2048;
    trans_pack_multi<<<dim3(blocks), dim3(256), 0, stream>>>(J, total);
  }
  conv_pack<<<dim3(4096), dim3(256), 0, stream>>>(enc, enc_p, enc_r,
                                                  (long)B_ * L_ * 512 / 8);
  mean_enc<<<dim3(128, 4), dim3(128), 0, stream>>>(enc, mean_b);
  gather_x<<<dim3(T_ * 128), dim3(64), 0, stream>>>(emb, caps, xbuf);

  // h0 -> hbuf[0] (packed K=512), c0 -> cbuf (f32)
  gemm_pk<1, 1, EPI_INIT><<<dim3(8, 16), dim3(256), 0, stream>>>(
      mean_b, WT_i, bix, (void*)hbuf, nullptr, cbuf, 128, 1024, 512, 0, 1.f);
  // Ea = exp2(ESCL*(enc @ W_v + b_v))  (bf16 row-major) — LAST consumer of enc_p
  gemm_pk<4, 2, EPI_EXP2><<<dim3(392, 4), dim3(256), 0, stream>>>(
      enc_p, WT_v, b_v, attv_b, nullptr, nullptr, B_ * L_, 512, 512, 512, 1.f);
  // xg = X_all @ [W_ih;Wx_s] + bias  (3200 x 2560 x 512, bf16, overlays enc_p)
  gemm_pk<4, 2, EPI_BF16><<<dim3(50, 20), dim3(256), 0, stream>>>(
      xbuf, WT_gx, bgx, xg, nullptr, nullptr, T_ * 128, 2560, 512, 2560, 1.f);

  // ---- persistent 25-step weight-stationary scan (8 groups x 32 blocks) ----
  scan_ws<<<dim3(256), dim3(256), 0, stream>>>(hbuf, WT_gh, xg, cbuf, Aag, projA, bar);

  // ---- batched attention pipeline ----
  // Eb = exp2(ESCL*([h|s]_all @ blockdiag(W_g, W_s_att) + [b_g|b_sa]))  (bf16)
  gemm_pk<4, 2, EPI_EXP2><<<dim3(50, 8), dim3(256), 0, stream>>>(
      Aag, WT_a, bax, agsw_b, nullptr, nullptr, T_ * 128, 1024, 1024, 1024, 1.f);
  // e-scores + softmax for all (b,t)
  e_batch<<<dim3(128, 25), dim3(256), 0, stream>>>(
      attv_b, agsw_b, w_a, clen, alphas, betas, alphas_raw, betas_raw);
  // WT_lo transpose (overlays dead xg) — must run after the scan
  {
    long n8 = (long)10240 * 512 / 8;
    trans_pack<<<dim3(2048), dim3(256), 0, stream>>>(W_Lo, nullptr, WT_lo,
                                                     10000, n8, 512, 512);
  }
  // ctx -> projA ctx-slots (reads enc ONCE, batched over all t)
  ctx_tail<<<dim3(128, 2), dim3(256), 0, stream>>>(alphas_raw, betas_raw, enc_r,
                                                   Aag, projA);
  // proj = x + [h|ctx] @ [W_Lh;W_Lz] + b   (3200 x 512 x 1024, packed out)
  gemm_pk<4, 2, EPI_PROJ><<<dim3(50, 4), dim3(256), 0, stream>>>(
      projA, WT_p, bpx, projb, xbuf, nullptr, T_ * 128, 512, 1024, 0, 1.f);
  // preds = proj @ W_Lo + b_Lo  (3200 x 10000 x 512)
  gemm_pk<4, 4, EPI_OUT><<<dim3(50, 40), dim3(256), 0, stream>>>(
      projb, WT_lo, b_Lo, preds, nullptr, nullptr, T_ * 128, V_, 512, 0, 1.f);
}

// Round 16
// 387.569 us; speedup vs baseline: 1.2059x; 1.0035x over previous
//
#include <hip/hip_runtime.h>
#include <hip/hip_bf16.h>
#include <cstdint>
#include <cstddef>

using bf16 = __hip_bfloat16;
typedef __attribute__((ext_vector_type(4))) float f32x4;
typedef __attribute__((ext_vector_type(8))) short bf16x8;

#define B_ 128
#define L_ 196
#define T_ 25
#define V_ 10000
#define ESCL 2.885390081777927f   // 2*log2(e): tanh(z) = 1 - 2/(1+exp2(z*ESCL))
#define LOG2E 1.4426950408889634f

__device__ __forceinline__ float b2f(short s) {
  unsigned u = ((unsigned)(unsigned short)s) << 16;
  return __uint_as_float(u);
}
__device__ __forceinline__ bf16 f2b(float f) { return __float2bfloat16(f); }
__device__ __forceinline__ short f2bs(float f) {
  return __builtin_bit_cast(short, __float2bfloat16(f));
}
__device__ __forceinline__ float sigf(float x) { return 1.f / (1.f + __expf(-x)); }
__device__ __forceinline__ float tanh_fast(float x) { return 1.f - 2.f / (1.f + __expf(2.f * x)); }

// sc1 write-through stores (push to L3); relaxed agent-scope loads for spin.
__device__ __forceinline__ void cst_u32(unsigned* p, unsigned v) {
  __hip_atomic_store(p, v, __ATOMIC_RELAXED, __HIP_MEMORY_SCOPE_AGENT);
}
__device__ __forceinline__ unsigned cld_u32(const unsigned* p) {
  return __hip_atomic_load((unsigned*)p, __ATOMIC_RELAXED, __HIP_MEMORY_SCOPE_AGENT);
}

// Fragment-packed layout: 16x32 tiles, tile-row-major; element (r,c) at
// (((r>>4)*KT + (c>>5))*64 + ((c&31)>>3)*16 + (r&15))*8 + (c&7).
__device__ __forceinline__ size_t pidx(int row, int col, int K) {
  int KT = K >> 5;
  return (((size_t)(row >> 4) * KT + (col >> 5)) * 64 +
          (size_t)(((col & 31) >> 3) * 16 + (row & 15))) * 8 + (col & 7);
}

__device__ __forceinline__ float wred_sum(float x) {
#pragma unroll
  for (int off = 32; off >= 1; off >>= 1) x += __shfl_xor(x, off, 64);
  return x;
}

// ---- monotone single-counter group barrier (32 blocks per group) ----
__device__ __forceinline__ void gbar_m(unsigned* bs, int mi, unsigned tgt) {
  asm volatile("s_waitcnt vmcnt(0)" ::: "memory");
  __syncthreads();
  if (threadIdx.x == 0) {
    unsigned* c = bs + mi * 64;       // 256B apart per group
    unsigned a = __hip_atomic_fetch_add(c, 1u, __ATOMIC_RELAXED,
                                        __HIP_MEMORY_SCOPE_AGENT);
    if (a + 1u < tgt) {
      while (cld_u32(c) < tgt) __builtin_amdgcn_s_sleep(1);
    }
  }
  __syncthreads();
}

// ---- persistent scan: weight-stationary, 256 blocks = 8 mi-groups x 32 di ----
__global__ __launch_bounds__(256) void scan_ws(
    bf16* __restrict__ hbuf,        // (T_+1) x (128x512 packed) h state
    const bf16* __restrict__ WT_gh, // 2560x512 packed (h-half weights)
    const bf16* __restrict__ xg,    // T_ x 128 x 2560 bf16 row-major: x@W + bias
    float* __restrict__ cbuf,       // 128x512 f32 cell state
    bf16* __restrict__ Aag,         // T_ x 128x1024 packed [h|s]  (post-scan)
    bf16* __restrict__ projA,       // T_ x 128x1024 packed [h|ctx] (post-scan)
    unsigned* __restrict__ bar)
{
  const int tid = threadIdx.x;
  const int wv = tid >> 6, lane = tid & 63;
  const int mi = blockIdx.x & 7;        // group: same XCD slot under round-robin
  const int di = blockIdx.x >> 3;       // 0..31 (cols di*16..+15)
  __shared__ f32x4 pacc[4][5][64];      // 20 KB split-K partials

  // ---- weight-stationary B fragments: bw[g][kk], kt = wv*4+kk ----
  bf16x8 bw[5][4];
#pragma unroll
  for (int g = 0; g < 5; g++)
#pragma unroll
    for (int kk = 0; kk < 4; kk++)
      bw[g][kk] = *(const bf16x8*)(const void*)(
          WT_gh + (size_t)(g * 32 + di) * 8192 + (size_t)(wv * 4 + kk) * 512 + lane * 8);

  const int el_r16 = lane & 15, el_r = lane >> 4;
  const int m_pw = mi * 16 + wv * 4 + el_r;
  const int d_pw = di * 16 + el_r16;
  const size_t qlo = pidx(m_pw, d_pw, 512);
  const size_t plo = pidx(m_pw, d_pw, 1024);
  const size_t phi = pidx(m_pw, 512 + d_pw, 1024);
  float* cp = cbuf + m_pw * 512 + d_pw;
  const size_t xoff = (size_t)m_pw * 2560 + d_pw;

  // preload xg for step 0
  const short* xr = (const short*)(const void*)(xg + xoff);
  float xv0 = b2f(xr[0]);
  float xv1 = b2f(xr[512]);
  float xv2 = b2f(xr[1024]);
  float xv3 = b2f(xr[1536]);
  float xv4 = b2f(xr[2048]);

  for (int tt = 0; tt < T_; ++tt) {
    const bf16* ap = hbuf + (size_t)tt * 65536 + (size_t)mi * 8192 + lane * 8;
    bf16x8 a0 = *(const bf16x8*)(const void*)(ap + (size_t)(wv * 4 + 0) * 512);
    bf16x8 a1 = *(const bf16x8*)(const void*)(ap + (size_t)(wv * 4 + 1) * 512);
    bf16x8 a2 = *(const bf16x8*)(const void*)(ap + (size_t)(wv * 4 + 2) * 512);
    bf16x8 a3 = *(const bf16x8*)(const void*)(ap + (size_t)(wv * 4 + 3) * 512);
    f32x4 acc[5];
#pragma unroll
    for (int g = 0; g < 5; g++) acc[g] = f32x4{0.f, 0.f, 0.f, 0.f};
#pragma unroll
    for (int g = 0; g < 5; g++) {
      acc[g] = __builtin_amdgcn_mfma_f32_16x16x32_bf16(a0, bw[g][0], acc[g], 0, 0, 0);
      acc[g] = __builtin_amdgcn_mfma_f32_16x16x32_bf16(a1, bw[g][1], acc[g], 0, 0, 0);
      acc[g] = __builtin_amdgcn_mfma_f32_16x16x32_bf16(a2, bw[g][2], acc[g], 0, 0, 0);
      acc[g] = __builtin_amdgcn_mfma_f32_16x16x32_bf16(a3, bw[g][3], acc[g], 0, 0, 0);
    }
#pragma unroll
    for (int g = 0; g < 5; g++) pacc[wv][g][lane] = acc[g];
    __syncthreads();
    float G0 = 0.f, G1 = 0.f, G2 = 0.f, G3 = 0.f, G4 = 0.f;
#pragma unroll
    for (int q = 0; q < 4; q++) {
      int sl = wv * 16 + el_r16;
      G0 += pacc[q][0][sl][el_r];
      G1 += pacc[q][1][sl][el_r];
      G2 += pacc[q][2][sl][el_r];
      G3 += pacc[q][3][sl][el_r];
      G4 += pacc[q][4][sl][el_r];
    }
    float cn = sigf(G1 + xv1) * (*cp) + sigf(G0 + xv0) * tanh_fast(G2 + xv2);
    float tcn = tanh_fast(cn);
    float hn = sigf(G3 + xv3) * tcn;
    float ss = sigf(G4 + xv4) * tcn;
    float hn1 = __shfl_down(hn, 1);
    float ss1 = __shfl_down(ss, 1);
    unsigned hp = 0, sp = 0;
    bool wr = !(el_r16 & 1);
    if (wr) {
      hp = (unsigned)(unsigned short)f2bs(hn) |
           ((unsigned)(unsigned short)f2bs(hn1) << 16);
      sp = (unsigned)(unsigned short)f2bs(ss) |
           ((unsigned)(unsigned short)f2bs(ss1) << 16);
      cst_u32((unsigned*)(void*)(hbuf + (size_t)(tt + 1) * 65536 + qlo), hp);
    }
    // prefetch xg for next step (independent of h); completes during barrier
    int tn = (tt + 1 < T_) ? tt + 1 : tt;
    const short* xrn = (const short*)(const void*)(xg + (size_t)tn * (128 * 2560) + xoff);
    float nx0 = b2f(xrn[0]);
    float nx1 = b2f(xrn[512]);
    float nx2 = b2f(xrn[1024]);
    float nx3 = b2f(xrn[1536]);
    float nx4 = b2f(xrn[2048]);
    if (tt < T_ - 1) gbar_m(bar, mi, 32u * (unsigned)(tt + 1));
    *cp = cn;
    if (wr) {
      bf16* pA = projA + (size_t)tt * 131072;
      bf16* AagT = Aag + (size_t)tt * 131072;
      *(unsigned*)(void*)(pA + plo) = hp;
      *(unsigned*)(void*)(AagT + plo) = hp;
      *(unsigned*)(void*)(AagT + phi) = sp;
    }
    xv0 = nx0; xv1 = nx1; xv2 = nx2; xv3 = nx3; xv4 = nx4;
  }
}

// ---- batched e-scores + softmax; grid (128, 25) ----
// attv/agsw store E = exp2(ESCL * preact):
//   e = Wsum - 2 * sum_d wa_d * rcp(fma(Ea, Eb, 1))
// |e| <= sum|wa| ~ 8, so softmax runs WITHOUT max subtraction (exp2 of +-12 safe).
__global__ __launch_bounds__(256) void e_batch(
    const bf16* __restrict__ attv, const bf16* __restrict__ agsw_all,
    const float* __restrict__ w_a, const int* __restrict__ clen,
    float* __restrict__ alphas, float* __restrict__ betas,
    float* __restrict__ alphas_raw, float* __restrict__ betas_raw)
{
  __shared__ float sh[200];
  __shared__ float red[4];
  int b = blockIdx.x, t = blockIdx.y;
  int tid = threadIdx.x, wv = tid >> 6, lane = tid & 63;
  const bf16* ag = agsw_all + ((size_t)t * 128 + b) * 1024;
  int a0 = lane * 8;
  float ag8[8], wa8[8], sw8[8];
  float wsum = 0.f;
  bf16x8 agv = *(const bf16x8*)(const void*)(ag + a0);
  bf16x8 swv = *(const bf16x8*)(const void*)(ag + 512 + a0);
#pragma unroll
  for (int j = 0; j < 8; j++) {
    ag8[j] = b2f(agv[j]);         // Eb
    wa8[j] = w_a[a0 + j];
    sw8[j] = b2f(swv[j]);         // Es
    wsum += wa8[j];
  }
  wsum = wred_sum(wsum);
  // main rows l < 196, 8 rows in flight per wave iteration
  for (int base = wv * 4; base < 196; base += 32) {
    bf16x8 av[8];
#pragma unroll
    for (int q = 0; q < 8; q++) {
      int l = base + ((q & 1) ? 16 : 0) + (q >> 1);
      if (l < 196)
        av[q] = *(const bf16x8*)(const void*)(attv + ((size_t)(b * 196 + l)) * 512 + a0);
    }
#pragma unroll
    for (int q = 0; q < 8; q++) {
      int l = base + ((q & 1) ? 16 : 0) + (q >> 1);
      if (l >= 196) continue;    // wave-uniform
      float part = 0.f;
#pragma unroll
      for (int j = 0; j < 8; j++) {
        float den = fmaf(b2f(av[q][j]), ag8[j], 1.f);
        part = fmaf(wa8[j], __builtin_amdgcn_rcpf(den), part);
      }
      part = wred_sum(part);
      if (lane == 0) sh[l] = wsum - 2.f * part;
    }
  }
  // s-row (l = 196): from registers
  if (wv == 0) {
    float part = 0.f;
#pragma unroll
    for (int j = 0; j < 8; j++) {
      float den = fmaf(sw8[j], ag8[j], 1.f);
      part = fmaf(wa8[j], __builtin_amdgcn_rcpf(den), part);
    }
    part = wred_sum(part);
    if (lane == 0) sh[196] = wsum - 2.f * part;
  }
  __syncthreads();
  // softmax WITHOUT max subtraction (e bounded)
  float v = (tid < 197) ? sh[tid] : 0.f;
  float p = (tid < 197) ? __builtin_amdgcn_exp2f(v * LOG2E) : 0.f;
  float sm = wred_sum(p);
  if (lane == 0) red[wv] = sm;
  __syncthreads();
  float inv = __builtin_amdgcn_rcpf(red[0] + red[1] + red[2] + red[3]);
  // Newton refine for full f32 accuracy of the normalization
  float sd = red[0] + red[1] + red[2] + red[3];
  inv = inv * (2.f - sd * inv);
  float a = p * inv;
  int dec = clen[b] - 1; if (dec < 1) dec = 1;
  float act = (t < dec) ? 1.f : 0.f;
  if (tid < 196) {
    alphas[(size_t)b * (T_ * L_) + (size_t)t * L_ + tid] = a * act;
    alphas_raw[(size_t)b * (T_ * L_) + (size_t)t * L_ + tid] = a;
  }
  if (tid == 196) {
    betas[b * T_ + t] = a * act;
    betas_raw[b * T_ + t] = a;
  }
}

// ---- tail: ctx(b,t,:) = alpha_raw(b,t,:) @ enc(b) + beta*s ; write projA ctx ----
__global__ __launch_bounds__(256) void ctx_tail(
    const float* __restrict__ alphas_raw, const float* __restrict__ betas_raw,
    const bf16* __restrict__ enc_r, const bf16* __restrict__ Aag,
    bf16* __restrict__ projA)
{
  int b = blockIdx.x, cs = blockIdx.y, tid = threadIdx.x;
  __shared__ float al[T_ * 200];
  for (int i = tid; i < T_ * 196; i += 256) {
    al[(i / 196) * 200 + (i % 196)] = alphas_raw[(size_t)b * (T_ * 196) + i];
  }
  __syncthreads();
  int ch = cs * 256 + tid;
  float acc[T_];
#pragma unroll
  for (int t = 0; t < T_; t++) acc[t] = 0.f;
  const short* ep = (const short*)(const void*)(enc_r) + (size_t)b * 196 * 512 + ch;
#pragma unroll 4
  for (int l = 0; l < 196; l++) {
    float e = b2f(ep[(size_t)l * 512]);
#pragma unroll
    for (int t = 0; t < T_; t++) acc[t] += al[t * 200 + l] * e;
  }
#pragma unroll
  for (int t = 0; t < T_; t++) {
    float beta = betas_raw[b * T_ + t];
    float sv = b2f(((const short*)(const void*)Aag)[(size_t)t * 131072 + pidx(b, 512 + ch, 1024)]);
    projA[(size_t)t * 131072 + pidx(b, 512 + ch, 1024)] = f2b(acc[t] + beta * sv);
  }
}

enum { EPI_F32 = 0, EPI_BF16 = 1, EPI_INIT = 2, EPI_PROJ = 3, EPI_OUT = 4, EPI_EXP2 = 5 };

// C = A (MxK packed) @ BT^T (BT: NxK packed), + bias.
template<int MFRAG, int NFRAG, int EPI>
__global__ __launch_bounds__(256) void gemm_pk(
    const bf16* __restrict__ A, const bf16* __restrict__ BT,
    const float* __restrict__ bias, void* __restrict__ Cp,
    const bf16* __restrict__ auxA, float* __restrict__ auxB,
    int M, int N, int K, int ldc, float oscale)
{
  const int lane = threadIdx.x & 63;
  const int wv = threadIdx.x >> 6;
  const int r16 = lane & 15;
  const int kg = lane >> 4;
  const int m0 = blockIdx.x * (MFRAG * 16);
  const int n0 = blockIdx.y * (NFRAG * 64) + wv * (NFRAG * 16);
  const int KT = K >> 5;

  f32x4 acc[MFRAG][NFRAG];
#pragma unroll
  for (int i = 0; i < MFRAG; i++)
#pragma unroll
    for (int j = 0; j < NFRAG; j++) acc[i][j] = f32x4{0.f, 0.f, 0.f, 0.f};

  const bf16* ap = A + (size_t)(m0 >> 4) * KT * 512 + lane * 8;
  const bf16* bp = BT + (size_t)(n0 >> 4) * KT * 512 + lane * 8;

#pragma unroll 4
  for (int kt = 0; kt < KT; kt++) {
    bf16x8 af[MFRAG], bfr[NFRAG];
#pragma unroll
    for (int i = 0; i < MFRAG; i++)
      af[i] = *(const bf16x8*)(const void*)(ap + ((size_t)i * KT + kt) * 512);
#pragma unroll
    for (int j = 0; j < NFRAG; j++)
      bfr[j] = *(const bf16x8*)(const void*)(bp + ((size_t)j * KT + kt) * 512);
#pragma unroll
    for (int i = 0; i < MFRAG; i++)
#pragma unroll
      for (int j = 0; j < NFRAG; j++)
        acc[i][j] = __builtin_amdgcn_mfma_f32_16x16x32_bf16(af[i], bfr[j], acc[i][j], 0, 0, 0);
  }

#pragma unroll
  for (int i = 0; i < MFRAG; i++)
#pragma unroll
    for (int j = 0; j < NFRAG; j++)
#pragma unroll
      for (int r = 0; r < 4; r++) {
        int m = m0 + i * 16 + kg * 4 + r;
        int n = n0 + j * 16 + r16;
        if (n >= N) continue;
        float v = acc[i][j][r] + bias[n];
        if constexpr (EPI == EPI_F32) {
          ((float*)Cp)[(size_t)m * ldc + n] = v * oscale;
        } else if constexpr (EPI == EPI_BF16) {
          ((bf16*)Cp)[(size_t)m * ldc + n] = f2b(v * oscale);
        } else if constexpr (EPI == EPI_EXP2) {
          ((bf16*)Cp)[(size_t)m * ldc + n] = f2b(__builtin_amdgcn_exp2f(ESCL * v));
        } else if constexpr (EPI == EPI_INIT) {
          float tv = tanhf(v);
          if (n < 512) ((bf16*)Cp)[pidx(m, n, 512)] = f2b(tv);   // h0 -> hbuf[0]
          else auxB[(size_t)m * 512 + (n - 512)] = tv;           // c0 (f32)
        } else if constexpr (EPI == EPI_PROJ) {
          v += b2f(((const short*)auxA)[pidx(m, n, 512)]);       // + x (xbuf)
          ((bf16*)Cp)[pidx(m, n, 512)] = f2b(v);
        } else {  // EPI_OUT: preds[b, t, n], row = t*128+b
          int t = m >> 7, b = m & 127;
          ((float*)Cp)[(size_t)b * (T_ * V_) + (size_t)t * V_ + n] = v;
        }
      }
}

// ---- fused multi-job packed-transpose ----
#define NJOBS 10
struct TJobs {
  const float* top[NJOBS];
  const float* bot[NJOBS];
  bf16* dst[NJOBS];
  int ncols[NJOBS];
  int ktop[NJOBS];
  int K[NJOBS];
  long cum[NJOBS + 1];
};

__global__ void trans_pack_multi(TJobs J, long total)
{
  for (long u = (long)blockIdx.x * blockDim.x + threadIdx.x; u < total;
       u += (long)gridDim.x * blockDim.x) {
    int j = 0;
#pragma unroll
    for (int q = 1; q < NJOBS; q++) j += (u >= J.cum[q]) ? 1 : 0;
    long t8 = u - J.cum[j];
    int K = J.K[j], KT = K >> 5, ktop = J.ktop[j], ncols = J.ncols[j];
    const float* top = J.top[j];
    const float* bot = J.bot[j];
    int r = (int)(t8 & 15);
    int kg = (int)((t8 >> 4) & 3);
    long tile = t8 >> 6;
    int kt = (int)(tile % KT);
    int rt = (int)(tile / KT);
    int n = rt * 16 + r;
    int kb = kt * 32 + kg * 8;
    bf16x8 out;
#pragma unroll
    for (int jj = 0; jj < 8; jj++) {
      int k = kb + jj;
      float v = 0.f;
      if (n < ncols) {
        if (k < ktop) { if (top) v = top[(size_t)k * ncols + n]; }
        else if (bot) { v = bot[(size_t)(k - ktop) * ncols + n]; }
      }
      out[jj] = f2bs(v);
    }
    *(bf16x8*)(void*)(J.dst[j] + t8 * 8) = out;
  }
}

// Packed-transpose (single job) — used post-scan for WT_lo.
__global__ void trans_pack(const float* __restrict__ top, const float* __restrict__ bot,
                           bf16* __restrict__ dst, int ncols, long nElem8, int ktop, int K)
{
  int KT = K >> 5;
  for (long t8 = (long)blockIdx.x * blockDim.x + threadIdx.x; t8 < nElem8;
       t8 += (long)gridDim.x * blockDim.x) {
    int r = (int)(t8 & 15);
    int kg = (int)((t8 >> 4) & 3);
    long tile = t8 >> 6;
    int kt = (int)(tile % KT);
    int rt = (int)(tile / KT);
    int n = rt * 16 + r;
    int kb = kt * 32 + kg * 8;
    bf16x8 out;
#pragma unroll
    for (int j = 0; j < 8; j++) {
      int k = kb + j;
      float v = 0.f;
      if (n < ncols) {
        if (k < ktop) { if (top) v = top[(size_t)k * ncols + n]; }
        else if (bot) { v = bot[(size_t)(k - ktop) * ncols + n]; }
      }
      out[j] = f2bs(v);
    }
    *(bf16x8*)(void*)(dst + t8 * 8) = out;
  }
}

// enc (f32 row-major) -> enc_p (bf16 packed) AND enc_r (bf16 row-major)
__global__ void conv_pack(const float* __restrict__ src, bf16* __restrict__ dst,
                          bf16* __restrict__ dst_row, long nElem8)
{
  for (long t8 = (long)blockIdx.x * blockDim.x + threadIdx.x; t8 < nElem8;
       t8 += (long)gridDim.x * blockDim.x) {
    int r = (int)(t8 & 15);
    int kg = (int)((t8 >> 4) & 3);
    long tile = t8 >> 6;
    int kt = (int)(tile & 15);           // KT = 16 (K=512)
    int rt = (int)(tile >> 4);
    size_t rowoff = ((size_t)(rt * 16 + r)) * 512 + kt * 32 + kg * 8;
    const float* s = src + rowoff;
    bf16x8 out;
#pragma unroll
    for (int j = 0; j < 8; j++) out[j] = f2bs(s[j]);
    *(bf16x8*)(void*)(dst + t8 * 8) = out;
    *(bf16x8*)(void*)(dst_row + rowoff) = out;
  }
}

__global__ void bias_comb(const float* __restrict__ b_lstm, const float* __restrict__ b_s,
                          const float* __restrict__ b_g, const float* __restrict__ b_sa,
                          const float* __restrict__ b_Lh, const float* __restrict__ b_Lz,
                          const float* __restrict__ b_ih, const float* __restrict__ b_ic,
                          float* __restrict__ bg, float* __restrict__ ba,
                          float* __restrict__ bp, float* __restrict__ bi)
{
  int i = blockIdx.x * blockDim.x + threadIdx.x;
  if (i < 2560) bg[i] = (i < 2048) ? b_lstm[i] : b_s[i - 2048];
  if (i < 1024) ba[i] = (i < 512) ? b_g[i] : b_sa[i - 512];
  if (i < 512)  bp[i] = b_Lh[i] + b_Lz[i];
  if (i < 1024) bi[i] = (i < 512) ? b_ih[i] : b_ic[i - 512];
}

__global__ __launch_bounds__(128) void mean_enc(const float* __restrict__ enc,
                                                bf16* __restrict__ mb)
{
  int b = blockIdx.x, c = blockIdx.y * 128 + threadIdx.x;
  float s = 0.f;
  for (int l = 0; l < L_; l++) s += enc[((size_t)b * L_ + l) * 512 + c];
  mb[pidx(b, c, 512)] = f2b(s * (1.f / (float)L_));
}

__global__ void gather_x(const float* __restrict__ emb, const int* __restrict__ caps,
                         bf16* __restrict__ xbuf)
{
  int tb = blockIdx.x;          // t*128 + b
  int t = tb >> 7, b = tb & 127;
  int word = caps[b * 26 + t];
  int c0 = threadIdx.x * 8;
  const float* src = emb + (size_t)word * 512 + c0;
  bf16* dst = xbuf + pidx(tb, c0, 512);
  bf16x8 out;
#pragma unroll
  for (int j = 0; j < 8; j++) out[j] = f2bs(src[j]);
  *(bf16x8*)(void*)dst = out;
}

extern "C" void kernel_launch(void* const* d_in, const int* in_sizes, int n_in,
                              void* d_out, int out_size, void* d_ws, size_t ws_size,
                              hipStream_t stream)
{
  const float* enc      = (const float*)d_in[0];
  const int*   caps     = (const int*)d_in[1];
  const int*   clen     = (const int*)d_in[2];
  const float* emb      = (const float*)d_in[3];
  const float* W_ih     = (const float*)d_in[4];
  const float* W_hh     = (const float*)d_in[5];
  const float* b_lstm   = (const float*)d_in[6];
  const float* Wx_s     = (const float*)d_in[7];
  const float* Wh_s     = (const float*)d_in[8];
  const float* b_s      = (const float*)d_in[9];
  const float* W_v      = (const float*)d_in[10];
  const float* b_v      = (const float*)d_in[11];
  const float* W_g      = (const float*)d_in[12];
  const float* b_g      = (const float*)d_in[13];
  const float* W_s_att  = (const float*)d_in[14];
  const float* b_sa     = (const float*)d_in[15];
  const float* w_a      = (const float*)d_in[16];
  const float* W_init_h = (const float*)d_in[17];
  const float* b_init_h = (const float*)d_in[18];
  const float* W_init_c = (const float*)d_in[19];
  const float* b_init_c = (const float*)d_in[20];
  const float* W_Lh     = (const float*)d_in[21];
  const float* b_Lh     = (const float*)d_in[22];
  const float* W_Lz     = (const float*)d_in[23];
  const float* b_Lz     = (const float*)d_in[24];
  const float* W_Lo     = (const float*)d_in[25];
  const float* b_Lo     = (const float*)d_in[26];

  float* preds  = (float*)d_out;
  float* alphas = preds + (size_t)B_ * T_ * V_;
  float* betas  = alphas + (size_t)B_ * T_ * L_;

  char* ws = (char*)d_ws;
  size_t off = 0;
  auto alloc = [&](size_t bytes) -> void* {
    void* p = ws + off;
    off = (off + bytes + 255) & ~(size_t)255;
    return p;
  };
  bf16*  enc_p  = (bf16*)alloc((size_t)B_ * L_ * 512 * 2);   // overlay region later
  bf16*  enc_r  = (bf16*)alloc((size_t)B_ * L_ * 512 * 2);
  bf16*  attv_b = (bf16*)alloc((size_t)B_ * L_ * 512 * 2);
  bf16*  WT_gx  = (bf16*)alloc((size_t)2560 * 512 * 2);
  bf16*  WT_gh  = (bf16*)alloc((size_t)2560 * 512 * 2);
  bf16*  WT_a   = (bf16*)alloc((size_t)1024 * 1024 * 2);
  bf16*  WT_p   = (bf16*)alloc((size_t)512 * 1024 * 2);
  bf16*  WT_v   = (bf16*)alloc((size_t)512 * 512 * 2);
  bf16*  WT_i   = (bf16*)alloc((size_t)1024 * 512 * 2);
  float* bgx    = (float*)alloc(2560 * 4);
  float* bax    = (float*)alloc(1024 * 4);
  float* bpx    = (float*)alloc(512 * 4);
  float* bix    = (float*)alloc(1024 * 4);
  bf16*  mean_b = (bf16*)alloc(128 * 512 * 2);
  bf16*  xbuf   = (bf16*)alloc((size_t)T_ * 128 * 512 * 2);
  bf16*  hbuf   = (bf16*)alloc((size_t)(T_ + 1) * 128 * 512 * 2);
  bf16*  projA  = (bf16*)alloc((size_t)T_ * 128 * 1024 * 2);
  bf16*  agsw_b = (bf16*)alloc((size_t)T_ * 128 * 1024 * 2);
  float* cbuf   = (float*)alloc(128 * 512 * 4);
  unsigned* bar = (unsigned*)alloc(8192);
  if (off > ws_size) return;  // loud validation failure if ws too small

  // Overlays in the dead enc_p region (25,690,112 B):
  //   xg (16,384,000) | Aag (6,553,600) | alphas_raw (2,508,800) | betas_raw (12,800)
  bf16*  xg         = (bf16*)enc_p;               // written AFTER att_v GEMM
  bf16*  Aag        = (bf16*)((char*)enc_p + 16384000);
  float* alphas_raw = (float*)((char*)enc_p + 22937600);
  float* betas_raw  = (float*)((char*)enc_p + 25446400);
  // Overlays in the dead xg region (post-scan):
  bf16*  WT_lo = xg;                              // 10,485,760 B (transposed post-scan)
  bf16*  projb = (bf16*)((char*)xg + 10485760);   // 3,276,800 B

  hipMemsetAsync(bar, 0, 8192, stream);

  // ---- prep ----
  bias_comb<<<dim3(10), dim3(256), 0, stream>>>(b_lstm, b_s, b_g, b_sa, b_Lh, b_Lz,
                                                b_init_h, b_init_c, bgx, bax, bpx, bix);
  // fused 10-job packed transpose
  {
    TJobs J;
    auto set = [&](int j, const float* top, const float* bot, bf16* dst,
                   int ncols, int nrows, int ktop, int K) {
      J.top[j] = top; J.bot[j] = bot; J.dst[j] = dst;
      J.ncols[j] = ncols; J.ktop[j] = ktop; J.K[j] = K;
      J.cum[j + 1] = J.cum[j] + (long)nrows * K / 8;
    };
    J.cum[0] = 0;
    set(0, W_ih, nullptr, WT_gx, 2048, 2048, 512, 512);
    set(1, Wx_s, nullptr, WT_gx + (size_t)2048 * 512, 512, 512, 512, 512);
    set(2, W_hh, nullptr, WT_gh, 2048, 2048, 512, 512);
    set(3, Wh_s, nullptr, WT_gh + (size_t)2048 * 512, 512, 512, 512, 512);
    set(4, W_Lh, W_Lz, WT_p, 512, 512, 512, 1024);
    set(5, W_g, nullptr, WT_a, 512, 512, 512, 1024);
    set(6, nullptr, W_s_att, WT_a + (size_t)512 * 1024, 512, 512, 512, 1024);
    set(7, W_v, nullptr, WT_v, 512, 512, 512, 512);
    set(8, W_init_h, nullptr, WT_i, 512, 512, 512, 512);
    set(9, W_init_c, nullptr, WT_i + (size_t)512 * 512, 512, 512, 512, 512);
    long total = J.cum[NJOBS];
    int blocks = (int)((total + 255) / 256);
    if (blocks > 2048) blocks = 2048;
    trans_pack_multi<<<dim3(blocks), dim3(256), 0, stream>>>(J, total);
  }
  conv_pack<<<dim3(4096), dim3(256), 0, stream>>>(enc, enc_p, enc_r,
                                                  (long)B_ * L_ * 512 / 8);
  mean_enc<<<dim3(128, 4), dim3(128), 0, stream>>>(enc, mean_b);
  gather_x<<<dim3(T_ * 128), dim3(64), 0, stream>>>(emb, caps, xbuf);

  // h0 -> hbuf[0] (packed K=512), c0 -> cbuf (f32)
  gemm_pk<1, 1, EPI_INIT><<<dim3(8, 16), dim3(256), 0, stream>>>(
      mean_b, WT_i, bix, (void*)hbuf, nullptr, cbuf, 128, 1024, 512, 0, 1.f);
  // Ea = exp2(ESCL*(enc @ W_v + b_v))  (bf16 row-major) — LAST consumer of enc_p
  gemm_pk<4, 2, EPI_EXP2><<<dim3(392, 4), dim3(256), 0, stream>>>(
      enc_p, WT_v, b_v, attv_b, nullptr, nullptr, B_ * L_, 512, 512, 512, 1.f);
  // xg = X_all @ [W_ih;Wx_s] + bias  (3200 x 2560 x 512, bf16, overlays enc_p)
  gemm_pk<4, 2, EPI_BF16><<<dim3(50, 20), dim3(256), 0, stream>>>(
      xbuf, WT_gx, bgx, xg, nullptr, nullptr, T_ * 128, 2560, 512, 2560, 1.f);

  // ---- persistent 25-step weight-stationary scan (8 groups x 32 blocks) ----
  scan_ws<<<dim3(256), dim3(256), 0, stream>>>(hbuf, WT_gh, xg, cbuf, Aag, projA, bar);

  // ---- batched attention pipeline ----
  // Eb = exp2(ESCL*([h|s]_all @ blockdiag(W_g, W_s_att) + [b_g|b_sa]))  (bf16)
  gemm_pk<4, 2, EPI_EXP2><<<dim3(50, 8), dim3(256), 0, stream>>>(
      Aag, WT_a, bax, agsw_b, nullptr, nullptr, T_ * 128, 1024, 1024, 1024, 1.f);
  // e-scores + softmax for all (b,t)
  e_batch<<<dim3(128, 25), dim3(256), 0, stream>>>(
      attv_b, agsw_b, w_a, clen, alphas, betas, alphas_raw, betas_raw);
  // WT_lo transpose (overlays dead xg) — must run after the scan
  {
    long n8 = (long)10240 * 512 / 8;
    trans_pack<<<dim3(2048), dim3(256), 0, stream>>>(W_Lo, nullptr, WT_lo,
                                                     10000, n8, 512, 512);
  }
  // ctx -> projA ctx-slots (reads enc ONCE, batched over all t)
  ctx_tail<<<dim3(128, 2), dim3(256), 0, stream>>>(alphas_raw, betas_raw, enc_r,
                                                   Aag, projA);
  // proj = x + [h|ctx] @ [W_Lh;W_Lz] + b   (3200 x 512 x 1024, packed out)
  gemm_pk<4, 2, EPI_PROJ><<<dim3(50, 4), dim3(256), 0, stream>>>(
      projA, WT_p, bpx, projb, xbuf, nullptr, T_ * 128, 512, 1024, 0, 1.f);
  // preds = proj @ W_Lo + b_Lo  (3200 x 10000 x 512)
  gemm_pk<4, 4, EPI_OUT><<<dim3(50, 40), dim3(256), 0, stream>>>(
      projb, WT_lo, b_Lo, preds, nullptr, nullptr, T_ * 128, V_, 512, 0, 1.f);
}